// Round 18
// baseline (383.440 us; speedup 1.0000x reference)
//
#include <hip/hip_runtime.h>
#include <hip/hip_bf16.h>

// MoE: B=4,S=4096,D=512,E=16,H=2048,top-2. T=16384 tokens, 32768 slots.
#define T_TOK 16384
#define DDIM  512
#define NEXP  16
#define HDIM  2048
#define NSLOT (T_TOK * 2)
#define NHB   128         // histogram blocks: NSLOT / 256

#define GBM 128           // gemm tile M (matches tile table)
#define GBN1 128          // gemm1 tile N (r18: was 256; gemm2's 128 shape is
                          // 1.5x faster at identical FLOPs -> clone it)
#define GBN2 128          // gemm2 tile N
#define BK  32            // gemm K-step
#define MAXTILE 272       // max m-tiles: 32768/128 + 16
#define TSLICE  272       // single slice (r16: slicing cost > its L3 benefit)

typedef __attribute__((ext_vector_type(8))) short short8;   // 8 x bf16
typedef __attribute__((ext_vector_type(4))) short short4v;
typedef __attribute__((ext_vector_type(4))) float f32x4;

__device__ inline short f2bf(float f) {
    __hip_bfloat16 h = __float2bfloat16(f);
    return *reinterpret_cast<short*>(&h);
}
__device__ inline float bf2f(short s) {
    unsigned u = ((unsigned)(unsigned short)s) << 16;
    union { unsigned u; float f; } c; c.u = u; return c.f;
}
// A&S 7.1.26 erf: |abs err| < 1.5e-7 (<< bf16 rounding of hbuf). ~14 VALU ops.
__device__ inline float erf_fast(float x) {
    float ax = fabsf(x);
    float t = 1.0f / fmaf(0.3275911f, ax, 1.0f);
    float p = fmaf(fmaf(fmaf(fmaf(1.061405429f, t, -1.453152027f), t,
                  1.421413741f), t, -0.284496736f), t, 0.254829592f) * t;
    float r = 1.0f - p * __expf(-ax * ax);
    return copysignf(r, x);
}
__device__ inline float geluf(float v) {   // exact-form gelu via fast erf
    return 0.5f * v * (1.0f + erf_fast(v * 0.70710678118654752440f));
}
// async global->LDS, 16B per lane. LDS dest = WAVE-UNIFORM base + lane*16.
__device__ inline void gload16(const void* g, void* l) {
    __builtin_amdgcn_global_load_lds(
        (const __attribute__((address_space(1))) void*)g,
        (__attribute__((address_space(3))) void*)l, 16, 0, 0);
}
// XCD-aware decode of a 1-D grid (lin over nx*tc blocks) into (tile y, chunk xn).
// HW assigns XCD = linear_wg_id % 8; equal lin%8 for a tile's n-chunks keeps
// them on ONE XCD -> A-tile L2/L3-resident (round-11: FETCH 74->37 MB, -25 us).
__device__ inline void xcd_decode(int lin, int nx, int tc, int& y, int& xn) {
    if ((tc & 7) == 0) {
        int tpx = tc >> 3;
        int k = lin & 7, j = lin >> 3;
        y = k * tpx + j % tpx;
        xn = j / tpx;
    } else {
        xn = lin % nx;
        y = lin / nx;
    }
}

// ---------------- routing ----------------
// wave-per-token gate: lane (g,q) = (d-quarter, expert). fp64 (tie-robust).
// Also emits xbf (bf16 copy of x): gate touches all of x anyway.
__global__ __launch_bounds__(256) void gate_kernel(
    const float* __restrict__ x, const float* __restrict__ wg,
    const float* __restrict__ bg, int* __restrict__ tok_e,
    float* __restrict__ tok_w, short* __restrict__ xbf)
{
    int wv = threadIdx.x >> 6, lane = threadIdx.x & 63;
    int t = blockIdx.x * 4 + wv;
    int g = lane >> 4, q = lane & 15;
    const float* xr = x + (size_t)t * DDIM + g * 128;
    const float* wr = wg + (size_t)g * 128 * NEXP + q;
    double a0 = 0, a1 = 0, a2 = 0, a3 = 0;
#pragma unroll
    for (int c = 0; c < 8; ++c) {
        float4 v0 = ((const float4*)xr)[c * 4 + 0];
        float4 v1 = ((const float4*)xr)[c * 4 + 1];
        float4 v2 = ((const float4*)xr)[c * 4 + 2];
        float4 v3 = ((const float4*)xr)[c * 4 + 3];
        const float* wp = wr + c * 16 * NEXP;
        a0 += (double)v0.x * (double)wp[0 * NEXP];
        a1 += (double)v0.y * (double)wp[1 * NEXP];
        a2 += (double)v0.z * (double)wp[2 * NEXP];
        a3 += (double)v0.w * (double)wp[3 * NEXP];
        a0 += (double)v1.x * (double)wp[4 * NEXP];
        a1 += (double)v1.y * (double)wp[5 * NEXP];
        a2 += (double)v1.z * (double)wp[6 * NEXP];
        a3 += (double)v1.w * (double)wp[7 * NEXP];
        a0 += (double)v2.x * (double)wp[8 * NEXP];
        a1 += (double)v2.y * (double)wp[9 * NEXP];
        a2 += (double)v2.z * (double)wp[10 * NEXP];
        a3 += (double)v2.w * (double)wp[11 * NEXP];
        a0 += (double)v3.x * (double)wp[12 * NEXP];
        a1 += (double)v3.y * (double)wp[13 * NEXP];
        a2 += (double)v3.z * (double)wp[14 * NEXP];
        a3 += (double)v3.w * (double)wp[15 * NEXP];
    }
    double a = ((a0 + a1) + (a2 + a3));
    a += __shfl_xor(a, 16, 64);
    a += __shfl_xor(a, 32, 64);
    a += (double)bg[q];
    double v0 = a; int i0 = q;
#pragma unroll
    for (int s = 1; s < 16; s <<= 1) {
        double ov = __shfl_xor(v0, s, 64);
        int oi = __shfl_xor(i0, s, 64);
        if (ov > v0 || (ov == v0 && oi < i0)) { v0 = ov; i0 = oi; }
    }
    double m2 = (q == i0) ? -1e300 : a;
    double v1 = m2; int i1 = q;
#pragma unroll
    for (int s = 1; s < 16; s <<= 1) {
        double ov = __shfl_xor(v1, s, 64);
        int oi = __shfl_xor(i1, s, 64);
        if (ov > v1 || (ov == v1 && oi < i1)) { v1 = ov; i1 = oi; }
    }
    if (lane == 0) {
        float ex = expf((float)(v1 - v0));      // <= 1
        float w0 = 1.0f / (1.0f + ex);
        tok_e[2 * t] = i0; tok_e[2 * t + 1] = i1;
        tok_w[2 * t] = w0; tok_w[2 * t + 1] = ex * w0;
    }
    // x -> bf16 (this wave's token, 8 elems/lane; x rows are L1-hot)
    {
        const float4* xs = (const float4*)(x + (size_t)t * DDIM + lane * 8);
        float4 u0 = xs[0], u1 = xs[1];
        short8 o;
        o[0] = f2bf(u0.x); o[1] = f2bf(u0.y); o[2] = f2bf(u0.z); o[3] = f2bf(u0.w);
        o[4] = f2bf(u1.x); o[5] = f2bf(u1.y); o[6] = f2bf(u1.z); o[7] = f2bf(u1.w);
        *(short8*)(xbf + (size_t)t * DDIM + lane * 8) = o;
    }
}

// per-block expert histogram (LDS atomics only)
__global__ __launch_bounds__(256) void hist_kernel(
    const int* __restrict__ tok_e, int* __restrict__ bhist)
{
    __shared__ int h[NEXP];
    if (threadIdx.x < NEXP) h[threadIdx.x] = 0;
    __syncthreads();
    atomicAdd(&h[tok_e[blockIdx.x * 256 + threadIdx.x]], 1);
    __syncthreads();
    if (threadIdx.x < NEXP) bhist[blockIdx.x * NEXP + threadIdx.x] = h[threadIdx.x];
}

// offs[0..16] = exclusive scan; offs[17] = ntiles; bbase[b][e] = scatter base.
__global__ void scan_kernel(const int* __restrict__ bhist, int* __restrict__ offs,
                            int* __restrict__ bbase, int* __restrict__ tile_e,
                            int* __restrict__ tile_m0)
{
    int tid = threadIdx.x;
    __shared__ int tot[NEXP];
    if (tid < NEXP) {
        int s = 0;
        for (int b = 0; b < NHB; ++b) s += bhist[b * NEXP + tid];
        tot[tid] = s;
    }
    __syncthreads();
    if (tid == 0) {
        int run = 0;
        for (int e = 0; e < NEXP; ++e) { offs[e] = run; run += tot[e]; }
        offs[NEXP] = run;   // == NSLOT
        int nt = 0;
        for (int e = 0; e < NEXP; ++e)
            for (int m = offs[e]; m < offs[e + 1]; m += GBM) {
                tile_e[nt] = e; tile_m0[nt] = m; ++nt;
            }
        offs[17] = nt;
    }
    __syncthreads();
    if (tid < NEXP) {
        int run = offs[tid];
        for (int b = 0; b < NHB; ++b) {
            bbase[b * NEXP + tid] = run;
            run += bhist[b * NEXP + tid];
        }
    }
}

// local rank via LDS atomic + precomputed block base
__global__ __launch_bounds__(256) void scatter_kernel(
    const int* __restrict__ tok_e, const float* __restrict__ tok_w,
    const int* __restrict__ bbase, int* __restrict__ list_tok,
    float* __restrict__ list_w, int* __restrict__ pos_tk)
{
    __shared__ int h[NEXP];
    if (threadIdx.x < NEXP) h[threadIdx.x] = 0;
    __syncthreads();
    int s = blockIdx.x * 256 + threadIdx.x;
    int e = tok_e[s];
    int r = atomicAdd(&h[e], 1);
    int pos = bbase[blockIdx.x * NEXP + e] + r;
    list_tok[pos] = s >> 1;
    list_w[pos] = tok_w[s];
    pos_tk[s] = pos;
}

// ---------------- pre-conversion ----------------

// transpose one [R][C] fp32 matrix per blockIdx.z into [C][R] bf16
__global__ void wtrans_kernel(const float* __restrict__ src, short* __restrict__ dst, int R, int C)
{
    __shared__ float t[32][33];
    int c0 = blockIdx.x * 32, r0 = blockIdx.y * 32;
    const float* s = src + (size_t)blockIdx.z * R * C;
    short* d = dst + (size_t)blockIdx.z * R * C;
    int cc = threadIdx.x & 31, rr = threadIdx.x >> 5;
#pragma unroll
    for (int pp = 0; pp < 4; ++pp)
        t[rr + pp * 8][cc] = s[(size_t)(r0 + rr + pp * 8) * C + c0 + cc];
    __syncthreads();
#pragma unroll
    for (int pp = 0; pp < 4; ++pp) {
        int c = rr + pp * 8;
        d[(size_t)(c0 + c) * R + r0 + cc] = f2bf(t[cc][c]);
    }
}

// ---------------- expert GEMMs: 3-buf counted-vmcnt, 128x128 tiles ----------
// r18: gemm1 cloned to gemm2's shape. Same-round A/B (r17): identical FLOPs,
// same schedule family, gemm2 (128x128, 48 KB, 3 blk/CU, 2 gloads/step) ran
// ~110us vs gemm1 (128x256, 72 KB, 2 blk/CU, 3 gloads/step) 164us.
// Both: steady vmcnt(2), 1 barrier/K-step, T2 both-sides swizzle, XCD swizzle.

__global__ __launch_bounds__(512) void gemm1_kernel(
    const short* __restrict__ xbf, const short* __restrict__ w1t,
    const float* __restrict__ b1, const int* __restrict__ offs,
    const int* __restrict__ tile_e, const int* __restrict__ tile_m0,
    const int* __restrict__ list_tok, short* __restrict__ hbuf,
    int h0, int hlen, int t0, int tc)
{
    int ty, xn;
    xcd_decode((int)blockIdx.x, hlen / GBN1, tc, ty, xn);
    int tb = t0 + ty;
    if (tb >= offs[17]) return;
    int e = tile_e[tb], m0 = tile_m0[tb];
    int rows = offs[e + 1] - m0; if (rows > GBM) rows = GBM;
    int n0 = xn * GBN1;
    int tid = threadIdx.x, l = tid & 63, w = tid >> 6;

    __shared__ __align__(16) short As[3][GBM * BK];    // 3 x 8 KiB
    __shared__ __align__(16) short Bs[3][GBN1 * BK];   // 3 x 8 KiB = 48 KB

    int arow = w * 16 + (l >> 2);
    int aslot = (l & 3) ^ ((arow >> 1) & 3);
    int tok = list_tok[m0 + (arow < rows ? arow : rows - 1)];
    const short* gA = xbf + (size_t)tok * DDIM + aslot * 8;
    int brow = w * 16 + (l >> 2);
    int bslot = (l & 3) ^ ((brow >> 1) & 3);
    const short* gB = w1t + ((size_t)e * HDIM + (size_t)(h0 + n0 + brow)) * DDIM + bslot * 8;

    int l15 = l & 15, kq = l >> 4;
    int aoff[4], boff[2];
#pragma unroll
    for (int mi = 0; mi < 4; ++mi) {
        int R = (w >> 2) * 64 + mi * 16 + l15;
        aoff[mi] = R * BK + ((kq ^ ((R >> 1) & 3)) * 8);
    }
#pragma unroll
    for (int ni = 0; ni < 2; ++ni) {
        int S = (w & 3) * 32 + ni * 16 + l15;
        boff[ni] = S * BK + ((kq ^ ((S >> 1) & 3)) * 8);
    }

    f32x4 vzero = {0.0f, 0.0f, 0.0f, 0.0f};
    f32x4 acc[4][2];
#pragma unroll
    for (int i = 0; i < 4; ++i)
#pragma unroll
        for (int j = 0; j < 2; ++j) acc[i][j] = vzero;

#define STAGE1(T, B) {                                            \
        gload16(gA + (T) * BK, &As[B][w * 512]);                  \
        gload16(gB + (T) * BK, &Bs[B][w * 512]); }

    const int nt = DDIM / BK;          // 16
    STAGE1(0, 0);
    STAGE1(1, 1);
    int cb = 0, sb = 2;
#pragma unroll 1
    for (int t = 0; t < nt; ++t) {
        if (t < nt - 1) asm volatile("s_waitcnt vmcnt(2)" ::: "memory");
        else            asm volatile("s_waitcnt vmcnt(0)" ::: "memory");
        __builtin_amdgcn_s_barrier();
        __builtin_amdgcn_sched_barrier(0);
        if (t + 2 < nt) STAGE1(t + 2, sb);
        const short* Ab = &As[cb][0];
        const short* Bb = &Bs[cb][0];
        short8 af[4], bv[2];
#pragma unroll
        for (int mi = 0; mi < 4; ++mi) af[mi] = *(const short8*)(Ab + aoff[mi]);
#pragma unroll
        for (int ni = 0; ni < 2; ++ni) bv[ni] = *(const short8*)(Bb + boff[ni]);
        __builtin_amdgcn_s_setprio(1);
#pragma unroll
        for (int mi = 0; mi < 4; ++mi)
#pragma unroll
            for (int ni = 0; ni < 2; ++ni)
                acc[mi][ni] = __builtin_amdgcn_mfma_f32_16x16x32_bf16(
                    af[mi], bv[ni], acc[mi][ni], 0, 0, 0);
        __builtin_amdgcn_s_setprio(0);
        cb = (cb == 2) ? 0 : cb + 1;
        sb = (sb == 2) ? 0 : sb + 1;
    }
#undef STAGE1

    int crow = (w >> 2) * 64 + (kq << 2);
    int ccol = (w & 3) * 32 + l15;
#pragma unroll
    for (int mi = 0; mi < 4; ++mi) {
#pragma unroll
        for (int ni = 0; ni < 2; ++ni) {
            int col = ccol + ni * 16;
            float bias = b1[e * HDIM + h0 + n0 + col];
#pragma unroll
            for (int j = 0; j < 4; ++j) {
                int row = crow + mi * 16 + j;
                if (row < rows) {
                    float v = acc[mi][ni][j] + bias;
                    hbuf[(size_t)(m0 + row) * hlen + (n0 + col)] = f2bf(geluf(v));
                }
            }
        }
    }
}

__global__ __launch_bounds__(512) void gemm2_kernel(
    const short* __restrict__ hbuf, const short* __restrict__ w2t,
    const float* __restrict__ b2, const int* __restrict__ offs,
    const int* __restrict__ tile_e, const int* __restrict__ tile_m0,
    const int* __restrict__ list_tok, const float* __restrict__ list_w,
    short* __restrict__ ybuf, float* __restrict__ out,
    int h0, int hlen, int mode, int t0, int tc)
{
    int ty, xn;
    xcd_decode((int)blockIdx.x, DDIM / GBN2, tc, ty, xn);
    int tb = t0 + ty;
    if (tb >= offs[17]) return;
    int e = tile_e[tb], m0 = tile_m0[tb];
    int rows = offs[e + 1] - m0; if (rows > GBM) rows = GBM;
    int n0 = xn * GBN2;                  // output d coordinate
    int tid = threadIdx.x, l = tid & 63, w = tid >> 6;

    __shared__ __align__(16) short As[3][GBM * BK];    // 3 x 8 KiB
    __shared__ __align__(16) short Bs[3][GBN2 * BK];   // 3 x 8 KiB = 48 KB total

    int arow = w * 16 + (l >> 2);
    int aslot = (l & 3) ^ ((arow >> 1) & 3);
    int aslotg = m0 + arow; if (aslotg >= NSLOT) aslotg = NSLOT - 1;
    const short* gA = hbuf + (size_t)aslotg * hlen + aslot * 8;
    int brow = w * 16 + (l >> 2);
    int bslot = (l & 3) ^ ((brow >> 1) & 3);
    const short* gB = w2t + ((size_t)e * DDIM + (size_t)(n0 + brow)) * HDIM + h0 + bslot * 8;

    int l15 = l & 15, kq = l >> 4;
    int aoff[4], boff[2];
#pragma unroll
    for (int mi = 0; mi < 4; ++mi) {
        int R = (w >> 2) * 64 + mi * 16 + l15;
        aoff[mi] = R * BK + ((kq ^ ((R >> 1) & 3)) * 8);
    }
#pragma unroll
    for (int ni = 0; ni < 2; ++ni) {
        int S = (w & 3) * 32 + ni * 16 + l15;
        boff[ni] = S * BK + ((kq ^ ((S >> 1) & 3)) * 8);
    }

    f32x4 vzero = {0.0f, 0.0f, 0.0f, 0.0f};
    f32x4 acc[4][2];
#pragma unroll
    for (int i = 0; i < 4; ++i)
#pragma unroll
        for (int j = 0; j < 2; ++j) acc[i][j] = vzero;

#define STAGE2(T, B) {                                            \
        gload16(gA + (T) * BK, &As[B][w * 512]);                  \
        gload16(gB + (T) * BK, &Bs[B][w * 512]); }

    const int nt = hlen / BK;          // 64 at hlen=2048
    STAGE2(0, 0);
    STAGE2(1, 1);
    int cb = 0, sb = 2;
#pragma unroll 1
    for (int t = 0; t < nt; ++t) {
        if (t < nt - 1) asm volatile("s_waitcnt vmcnt(2)" ::: "memory");
        else            asm volatile("s_waitcnt vmcnt(0)" ::: "memory");
        __builtin_amdgcn_s_barrier();
        __builtin_amdgcn_sched_barrier(0);
        if (t + 2 < nt) STAGE2(t + 2, sb);
        const short* Ab = &As[cb][0];
        const short* Bb = &Bs[cb][0];
        short8 af[4], bv[2];
#pragma unroll
        for (int mi = 0; mi < 4; ++mi) af[mi] = *(const short8*)(Ab + aoff[mi]);
#pragma unroll
        for (int ni = 0; ni < 2; ++ni) bv[ni] = *(const short8*)(Bb + boff[ni]);
        __builtin_amdgcn_s_setprio(1);
#pragma unroll
        for (int mi = 0; mi < 4; ++mi)
#pragma unroll
            for (int ni = 0; ni < 2; ++ni)
                acc[mi][ni] = __builtin_amdgcn_mfma_f32_16x16x32_bf16(
                    af[mi], bv[ni], acc[mi][ni], 0, 0, 0);
        __builtin_amdgcn_s_setprio(0);
        cb = (cb == 2) ? 0 : cb + 1;
        sb = (sb == 2) ? 0 : sb + 1;
    }
#undef STAGE2

    int crow = (w >> 2) * 64 + (kq << 2);
    int ccol = (w & 3) * 32 + l15;
#pragma unroll
    for (int mi = 0; mi < 4; ++mi) {
#pragma unroll
        for (int ni = 0; ni < 2; ++ni) {
            int col = ccol + ni * 16;
            float bias = (h0 == 0) ? b2[e * DDIM + n0 + col] : 0.0f;
#pragma unroll
            for (int j = 0; j < 4; ++j) {
                int row = crow + mi * 16 + j;
                if (row < rows) {
                    float v = acc[mi][ni][j] + bias;
                    if (mode == 0) {  // full-K path: single bf16 write by slot
                        ybuf[(size_t)(m0 + row) * DDIM + n0 + col] = f2bf(v);
                    } else {          // atomic path: token/weight from global (L2)
                        int tokr = list_tok[m0 + row];
                        float wr = list_w[m0 + row];
                        atomicAdd(&out[(size_t)tokr * DDIM + n0 + col], wr * v);
                    }
                }
            }
        }
    }
}

// out[t] = w0*ybuf[pos0] + w1*ybuf[pos1]  (ybuf bf16, 8 cols/thread)
__global__ __launch_bounds__(256) void combine_kernel(
    const short* __restrict__ ybuf, const int* __restrict__ pos_tk,
    const float* __restrict__ tok_w, float* __restrict__ out)
{
    int i = blockIdx.x * 256 + threadIdx.x;   // over T_TOK * 64 units
    int t = i >> 6, c = (i & 63) * 8;
    float w0 = tok_w[2 * t], w1 = tok_w[2 * t + 1];
    int p0 = pos_tk[2 * t], p1 = pos_tk[2 * t + 1];
    short8 a = *(const short8*)(ybuf + (size_t)p0 * DDIM + c);
    short8 b = *(const short8*)(ybuf + (size_t)p1 * DDIM + c);
    float4 o0, o1;
    float* op = (float*)&o0;
#pragma unroll
    for (int j = 0; j < 4; ++j) op[j] = w0 * bf2f(a[j]) + w1 * bf2f(b[j]);
    float* op1 = (float*)&o1;
#pragma unroll
    for (int j = 0; j < 4; ++j) op1[j] = w0 * bf2f(a[4 + j]) + w1 * bf2f(b[4 + j]);
    float4* ob = (float4*)(out + (size_t)t * DDIM + c);
    ob[0] = o0;
    ob[1] = o1;
}

// ---------------- launch ----------------

extern "C" void kernel_launch(void* const* d_in, const int* in_sizes, int n_in,
                              void* d_out, int out_size, void* d_ws, size_t ws_size,
                              hipStream_t stream)
{
    const float* x  = (const float*)d_in[0];
    const float* wg = (const float*)d_in[1];
    const float* bg = (const float*)d_in[2];
    const float* w1 = (const float*)d_in[3];
    const float* b1 = (const float*)d_in[4];
    const float* w2 = (const float*)d_in[5];
    const float* b2 = (const float*)d_in[6];
    float* out = (float*)d_out;

    char* p = (char*)d_ws;
    int* offs     = (int*)(p + 128);            // 32 ints
    int* tile_e   = (int*)(p + 256);            // 512 ints
    int* tile_m0  = (int*)(p + 2304);           // 512 ints
    int* bhist    = (int*)(p + 8192);           // 8 KiB
    int* bbase    = (int*)(p + 16384);          // 8 KiB
    int* tok_e    = (int*)(p + 32768);          // 128 KiB
    float* tok_w  = (float*)(p + 32768 + 131072);
    int* list_tok = (int*)(p + 32768 + 262144);
    float* list_w = (float*)(p + 32768 + 393216);
    int* pos_tk   = (int*)(p + 32768 + 524288);
    short* xbf    = (short*)(p + 32768 + 655360);             // 16 MiB
    short* w1t    = xbf + (size_t)T_TOK * DDIM;               // 32 MiB
    short* w2t    = w1t + (size_t)NEXP * DDIM * HDIM;         // 32 MiB
    char* after   = (char*)(w2t + (size_t)NEXP * DDIM * HDIM);
    size_t fixed  = (size_t)(after - p);

    // mode 0: full-K gemm2 + bf16 ybuf + combine (needs hbuf 134 MB + ybuf 33.5 MB)
    // mode 1 fallback: h-chunked gemm2 with atomic out accumulate.
    int mode, hlen = HDIM;
    if (fixed + (size_t)NSLOT * DDIM * 2 + (size_t)NSLOT * HDIM * 2 <= ws_size) {
        mode = 0;
    } else {
        mode = 1;
        hlen = 0;
        for (int hl = HDIM; hl >= 256; hl >>= 1)
            if (fixed + (size_t)NSLOT * hl * 2 <= ws_size) { hlen = hl; break; }
    }
    short* ybuf = (short*)after;
    short* hbuf = (mode == 0) ? (short*)(after + (size_t)NSLOT * DDIM * 2) : (short*)after;

    if (!hlen) { hipMemsetAsync(d_out, 0, (size_t)out_size * sizeof(float), stream); return; }
    if (mode == 1) hipMemsetAsync(d_out, 0, (size_t)out_size * sizeof(float), stream);

    gate_kernel<<<T_TOK / 4, 256, 0, stream>>>(x, wg, bg, tok_e, tok_w, xbf);
    hist_kernel<<<NHB, 256, 0, stream>>>(tok_e, bhist);
    scan_kernel<<<1, 64, 0, stream>>>(bhist, offs, bbase, tile_e, tile_m0);
    scatter_kernel<<<NHB, 256, 0, stream>>>(tok_e, tok_w, bbase, list_tok, list_w, pos_tk);
    wtrans_kernel<<<dim3(HDIM / 32, DDIM / 32, NEXP), 256, 0, stream>>>(w1, w1t, DDIM, HDIM);
    wtrans_kernel<<<dim3(DDIM / 32, HDIM / 32, NEXP), 256, 0, stream>>>(w2, w2t, HDIM, DDIM);

    // single slice; XCD decode keeps each tile's n-chunks on one XCD.
    for (int h0 = 0; h0 < HDIM; h0 += hlen) {
        for (int t0 = 0; t0 < MAXTILE; t0 += TSLICE) {
            int tc = MAXTILE - t0; if (tc > TSLICE) tc = TSLICE;
            gemm1_kernel<<<(hlen / GBN1) * tc, 512, 0, stream>>>(
                xbf, w1t, b1, offs, tile_e, tile_m0, list_tok, hbuf, h0, hlen, t0, tc);
            gemm2_kernel<<<(DDIM / GBN2) * tc, 512, 0, stream>>>(
                hbuf, w2t, b2, offs, tile_e, tile_m0, list_tok, list_w,
                ybuf, out, h0, hlen, mode, t0, tc);
        }
    }
    if (mode == 0)
        combine_kernel<<<T_TOK * 64 / 256, 256, 0, stream>>>(ybuf, pos_tk, tok_w, out);
}

// Round 19
// 357.471 us; speedup vs baseline: 1.0726x; 1.0726x over previous
//
#include <hip/hip_runtime.h>
#include <hip/hip_bf16.h>

// MoE: B=4,S=4096,D=512,E=16,H=2048,top-2. T=16384 tokens, 32768 slots.
#define T_TOK 16384
#define DDIM  512
#define NEXP  16
#define HDIM  2048
#define NSLOT (T_TOK * 2)
#define NHB   128         // histogram blocks: NSLOT / 256

#define GBM 128           // gemm tile M (matches tile table)
#define GBN1 128          // gemm1 tile N
#define GBN2 128          // gemm2 tile N
#define BK  32            // gemm K-step
#define MAXTILE 272       // max m-tiles: 32768/128 + 16
#define TSLICE  272       // single slice (r16: slicing cost > its L3 benefit)

typedef __attribute__((ext_vector_type(8))) short short8;   // 8 x bf16
typedef __attribute__((ext_vector_type(4))) short short4v;
typedef __attribute__((ext_vector_type(4))) float f32x4;

__device__ inline short f2bf(float f) {
    __hip_bfloat16 h = __float2bfloat16(f);
    return *reinterpret_cast<short*>(&h);
}
__device__ inline float bf2f(short s) {
    unsigned u = ((unsigned)(unsigned short)s) << 16;
    union { unsigned u; float f; } c; c.u = u; return c.f;
}
// A&S 7.1.26 erf: |abs err| < 1.5e-7 (<< bf16 rounding of hbuf). ~14 VALU ops.
__device__ inline float erf_fast(float x) {
    float ax = fabsf(x);
    float t = 1.0f / fmaf(0.3275911f, ax, 1.0f);
    float p = fmaf(fmaf(fmaf(fmaf(1.061405429f, t, -1.453152027f), t,
                  1.421413741f), t, -0.284496736f), t, 0.254829592f) * t;
    float r = 1.0f - p * __expf(-ax * ax);
    return copysignf(r, x);
}
__device__ inline float geluf(float v) {   // exact-form gelu via fast erf
    return 0.5f * v * (1.0f + erf_fast(v * 0.70710678118654752440f));
}
// async global->LDS, 16B per lane. LDS dest = WAVE-UNIFORM base + lane*16.
__device__ inline void gload16(const void* g, void* l) {
    __builtin_amdgcn_global_load_lds(
        (const __attribute__((address_space(1))) void*)g,
        (__attribute__((address_space(3))) void*)l, 16, 0, 0);
}
// XCD-aware decode, TILE-MAJOR within each XCD (r19).
// lin%8 = XCD (HW round-robin). r18 pm: chunk-major order swept 34 X-panels
// per chunk pass (4.4 MB > 4 MB L2) -> X re-fetched from L3 every pass
// (FETCH 198 MB vs 33 compulsory). Tile-major: a tile's nx chunks are
// temporally adjacent on one XCD -> ~6-tile working set (<1 MB) L2-hits.
__device__ inline void xcd_decode(int lin, int nx, int tc, int& y, int& xn) {
    if ((tc & 7) == 0) {
        int tpx = tc >> 3;
        int k = lin & 7, j = lin >> 3;
        y = k * tpx + j / nx;
        xn = j % nx;
    } else {
        xn = lin % nx;
        y = lin / nx;
    }
}

// ---------------- routing ----------------
// wave-per-token gate: lane (g,q) = (d-quarter, expert). fp64 (tie-robust).
// Also emits xbf (bf16 copy of x): gate touches all of x anyway.
__global__ __launch_bounds__(256) void gate_kernel(
    const float* __restrict__ x, const float* __restrict__ wg,
    const float* __restrict__ bg, int* __restrict__ tok_e,
    float* __restrict__ tok_w, short* __restrict__ xbf)
{
    int wv = threadIdx.x >> 6, lane = threadIdx.x & 63;
    int t = blockIdx.x * 4 + wv;
    int g = lane >> 4, q = lane & 15;
    const float* xr = x + (size_t)t * DDIM + g * 128;
    const float* wr = wg + (size_t)g * 128 * NEXP + q;
    double a0 = 0, a1 = 0, a2 = 0, a3 = 0;
#pragma unroll
    for (int c = 0; c < 8; ++c) {
        float4 v0 = ((const float4*)xr)[c * 4 + 0];
        float4 v1 = ((const float4*)xr)[c * 4 + 1];
        float4 v2 = ((const float4*)xr)[c * 4 + 2];
        float4 v3 = ((const float4*)xr)[c * 4 + 3];
        const float* wp = wr + c * 16 * NEXP;
        a0 += (double)v0.x * (double)wp[0 * NEXP];
        a1 += (double)v0.y * (double)wp[1 * NEXP];
        a2 += (double)v0.z * (double)wp[2 * NEXP];
        a3 += (double)v0.w * (double)wp[3 * NEXP];
        a0 += (double)v1.x * (double)wp[4 * NEXP];
        a1 += (double)v1.y * (double)wp[5 * NEXP];
        a2 += (double)v1.z * (double)wp[6 * NEXP];
        a3 += (double)v1.w * (double)wp[7 * NEXP];
        a0 += (double)v2.x * (double)wp[8 * NEXP];
        a1 += (double)v2.y * (double)wp[9 * NEXP];
        a2 += (double)v2.z * (double)wp[10 * NEXP];
        a3 += (double)v2.w * (double)wp[11 * NEXP];
        a0 += (double)v3.x * (double)wp[12 * NEXP];
        a1 += (double)v3.y * (double)wp[13 * NEXP];
        a2 += (double)v3.z * (double)wp[14 * NEXP];
        a3 += (double)v3.w * (double)wp[15 * NEXP];
    }
    double a = ((a0 + a1) + (a2 + a3));
    a += __shfl_xor(a, 16, 64);
    a += __shfl_xor(a, 32, 64);
    a += (double)bg[q];
    double v0 = a; int i0 = q;
#pragma unroll
    for (int s = 1; s < 16; s <<= 1) {
        double ov = __shfl_xor(v0, s, 64);
        int oi = __shfl_xor(i0, s, 64);
        if (ov > v0 || (ov == v0 && oi < i0)) { v0 = ov; i0 = oi; }
    }
    double m2 = (q == i0) ? -1e300 : a;
    double v1 = m2; int i1 = q;
#pragma unroll
    for (int s = 1; s < 16; s <<= 1) {
        double ov = __shfl_xor(v1, s, 64);
        int oi = __shfl_xor(i1, s, 64);
        if (ov > v1 || (ov == v1 && oi < i1)) { v1 = ov; i1 = oi; }
    }
    if (lane == 0) {
        float ex = expf((float)(v1 - v0));      // <= 1
        float w0 = 1.0f / (1.0f + ex);
        tok_e[2 * t] = i0; tok_e[2 * t + 1] = i1;
        tok_w[2 * t] = w0; tok_w[2 * t + 1] = ex * w0;
    }
    // x -> bf16 (this wave's token, 8 elems/lane; x rows are L1-hot)
    {
        const float4* xs = (const float4*)(x + (size_t)t * DDIM + lane * 8);
        float4 u0 = xs[0], u1 = xs[1];
        short8 o;
        o[0] = f2bf(u0.x); o[1] = f2bf(u0.y); o[2] = f2bf(u0.z); o[3] = f2bf(u0.w);
        o[4] = f2bf(u1.x); o[5] = f2bf(u1.y); o[6] = f2bf(u1.z); o[7] = f2bf(u1.w);
        *(short8*)(xbf + (size_t)t * DDIM + lane * 8) = o;
    }
}

// per-block expert histogram (LDS atomics only)
__global__ __launch_bounds__(256) void hist_kernel(
    const int* __restrict__ tok_e, int* __restrict__ bhist)
{
    __shared__ int h[NEXP];
    if (threadIdx.x < NEXP) h[threadIdx.x] = 0;
    __syncthreads();
    atomicAdd(&h[tok_e[blockIdx.x * 256 + threadIdx.x]], 1);
    __syncthreads();
    if (threadIdx.x < NEXP) bhist[blockIdx.x * NEXP + threadIdx.x] = h[threadIdx.x];
}

// offs[0..16] = exclusive scan; offs[17] = ntiles; bbase[b][e] = scatter base.
__global__ void scan_kernel(const int* __restrict__ bhist, int* __restrict__ offs,
                            int* __restrict__ bbase, int* __restrict__ tile_e,
                            int* __restrict__ tile_m0)
{
    int tid = threadIdx.x;
    __shared__ int tot[NEXP];
    if (tid < NEXP) {
        int s = 0;
        for (int b = 0; b < NHB; ++b) s += bhist[b * NEXP + tid];
        tot[tid] = s;
    }
    __syncthreads();
    if (tid == 0) {
        int run = 0;
        for (int e = 0; e < NEXP; ++e) { offs[e] = run; run += tot[e]; }
        offs[NEXP] = run;   // == NSLOT
        int nt = 0;
        for (int e = 0; e < NEXP; ++e)
            for (int m = offs[e]; m < offs[e + 1]; m += GBM) {
                tile_e[nt] = e; tile_m0[nt] = m; ++nt;
            }
        offs[17] = nt;
    }
    __syncthreads();
    if (tid < NEXP) {
        int run = offs[tid];
        for (int b = 0; b < NHB; ++b) {
            bbase[b * NEXP + tid] = run;
            run += bhist[b * NEXP + tid];
        }
    }
}

// local rank via LDS atomic + precomputed block base
__global__ __launch_bounds__(256) void scatter_kernel(
    const int* __restrict__ tok_e, const float* __restrict__ tok_w,
    const int* __restrict__ bbase, int* __restrict__ list_tok,
    float* __restrict__ list_w, int* __restrict__ pos_tk)
{
    __shared__ int h[NEXP];
    if (threadIdx.x < NEXP) h[threadIdx.x] = 0;
    __syncthreads();
    int s = blockIdx.x * 256 + threadIdx.x;
    int e = tok_e[s];
    int r = atomicAdd(&h[e], 1);
    int pos = bbase[blockIdx.x * NEXP + e] + r;
    list_tok[pos] = s >> 1;
    list_w[pos] = tok_w[s];
    pos_tk[s] = pos;
}

// ---------------- pre-conversion ----------------

// transpose one [R][C] fp32 matrix per blockIdx.z into [C][R] bf16
__global__ void wtrans_kernel(const float* __restrict__ src, short* __restrict__ dst, int R, int C)
{
    __shared__ float t[32][33];
    int c0 = blockIdx.x * 32, r0 = blockIdx.y * 32;
    const float* s = src + (size_t)blockIdx.z * R * C;
    short* d = dst + (size_t)blockIdx.z * R * C;
    int cc = threadIdx.x & 31, rr = threadIdx.x >> 5;
#pragma unroll
    for (int pp = 0; pp < 4; ++pp)
        t[rr + pp * 8][cc] = s[(size_t)(r0 + rr + pp * 8) * C + c0 + cc];
    __syncthreads();
#pragma unroll
    for (int pp = 0; pp < 4; ++pp) {
        int c = rr + pp * 8;
        d[(size_t)(c0 + c) * R + r0 + cc] = f2bf(t[cc][c]);
    }
}

// ---------------- expert GEMMs: 3-buf counted-vmcnt, 128x128 tiles ----------
// Both: steady vmcnt(2), 1 barrier/K-step, T2 both-sides swizzle,
// tile-major XCD swizzle (r19). 48 KB LDS -> 3 blk/CU.

__global__ __launch_bounds__(512) void gemm1_kernel(
    const short* __restrict__ xbf, const short* __restrict__ w1t,
    const float* __restrict__ b1, const int* __restrict__ offs,
    const int* __restrict__ tile_e, const int* __restrict__ tile_m0,
    const int* __restrict__ list_tok, short* __restrict__ hbuf,
    int h0, int hlen, int t0, int tc)
{
    int ty, xn;
    xcd_decode((int)blockIdx.x, hlen / GBN1, tc, ty, xn);
    int tb = t0 + ty;
    if (tb >= offs[17]) return;
    int e = tile_e[tb], m0 = tile_m0[tb];
    int rows = offs[e + 1] - m0; if (rows > GBM) rows = GBM;
    int n0 = xn * GBN1;
    int tid = threadIdx.x, l = tid & 63, w = tid >> 6;

    __shared__ __align__(16) short As[3][GBM * BK];    // 3 x 8 KiB
    __shared__ __align__(16) short Bs[3][GBN1 * BK];   // 3 x 8 KiB = 48 KB

    int arow = w * 16 + (l >> 2);
    int aslot = (l & 3) ^ ((arow >> 1) & 3);
    int tok = list_tok[m0 + (arow < rows ? arow : rows - 1)];
    const short* gA = xbf + (size_t)tok * DDIM + aslot * 8;
    int brow = w * 16 + (l >> 2);
    int bslot = (l & 3) ^ ((brow >> 1) & 3);
    const short* gB = w1t + ((size_t)e * HDIM + (size_t)(h0 + n0 + brow)) * DDIM + bslot * 8;

    int l15 = l & 15, kq = l >> 4;
    int aoff[4], boff[2];
#pragma unroll
    for (int mi = 0; mi < 4; ++mi) {
        int R = (w >> 2) * 64 + mi * 16 + l15;
        aoff[mi] = R * BK + ((kq ^ ((R >> 1) & 3)) * 8);
    }
#pragma unroll
    for (int ni = 0; ni < 2; ++ni) {
        int S = (w & 3) * 32 + ni * 16 + l15;
        boff[ni] = S * BK + ((kq ^ ((S >> 1) & 3)) * 8);
    }

    f32x4 vzero = {0.0f, 0.0f, 0.0f, 0.0f};
    f32x4 acc[4][2];
#pragma unroll
    for (int i = 0; i < 4; ++i)
#pragma unroll
        for (int j = 0; j < 2; ++j) acc[i][j] = vzero;

#define STAGE1(T, B) {                                            \
        gload16(gA + (T) * BK, &As[B][w * 512]);                  \
        gload16(gB + (T) * BK, &Bs[B][w * 512]); }

    const int nt = DDIM / BK;          // 16
    STAGE1(0, 0);
    STAGE1(1, 1);
    int cb = 0, sb = 2;
#pragma unroll 1
    for (int t = 0; t < nt; ++t) {
        if (t < nt - 1) asm volatile("s_waitcnt vmcnt(2)" ::: "memory");
        else            asm volatile("s_waitcnt vmcnt(0)" ::: "memory");
        __builtin_amdgcn_s_barrier();
        __builtin_amdgcn_sched_barrier(0);
        if (t + 2 < nt) STAGE1(t + 2, sb);
        const short* Ab = &As[cb][0];
        const short* Bb = &Bs[cb][0];
        short8 af[4], bv[2];
#pragma unroll
        for (int mi = 0; mi < 4; ++mi) af[mi] = *(const short8*)(Ab + aoff[mi]);
#pragma unroll
        for (int ni = 0; ni < 2; ++ni) bv[ni] = *(const short8*)(Bb + boff[ni]);
        __builtin_amdgcn_s_setprio(1);
#pragma unroll
        for (int mi = 0; mi < 4; ++mi)
#pragma unroll
            for (int ni = 0; ni < 2; ++ni)
                acc[mi][ni] = __builtin_amdgcn_mfma_f32_16x16x32_bf16(
                    af[mi], bv[ni], acc[mi][ni], 0, 0, 0);
        __builtin_amdgcn_s_setprio(0);
        cb = (cb == 2) ? 0 : cb + 1;
        sb = (sb == 2) ? 0 : sb + 1;
    }
#undef STAGE1

    int crow = (w >> 2) * 64 + (kq << 2);
    int ccol = (w & 3) * 32 + l15;
#pragma unroll
    for (int mi = 0; mi < 4; ++mi) {
#pragma unroll
        for (int ni = 0; ni < 2; ++ni) {
            int col = ccol + ni * 16;
            float bias = b1[e * HDIM + h0 + n0 + col];
#pragma unroll
            for (int j = 0; j < 4; ++j) {
                int row = crow + mi * 16 + j;
                if (row < rows) {
                    float v = acc[mi][ni][j] + bias;
                    hbuf[(size_t)(m0 + row) * hlen + (n0 + col)] = f2bf(geluf(v));
                }
            }
        }
    }
}

__global__ __launch_bounds__(512) void gemm2_kernel(
    const short* __restrict__ hbuf, const short* __restrict__ w2t,
    const float* __restrict__ b2, const int* __restrict__ offs,
    const int* __restrict__ tile_e, const int* __restrict__ tile_m0,
    const int* __restrict__ list_tok, const float* __restrict__ list_w,
    short* __restrict__ ybuf, float* __restrict__ out,
    int h0, int hlen, int mode, int t0, int tc)
{
    int ty, xn;
    xcd_decode((int)blockIdx.x, DDIM / GBN2, tc, ty, xn);
    int tb = t0 + ty;
    if (tb >= offs[17]) return;
    int e = tile_e[tb], m0 = tile_m0[tb];
    int rows = offs[e + 1] - m0; if (rows > GBM) rows = GBM;
    int n0 = xn * GBN2;                  // output d coordinate
    int tid = threadIdx.x, l = tid & 63, w = tid >> 6;

    __shared__ __align__(16) short As[3][GBM * BK];    // 3 x 8 KiB
    __shared__ __align__(16) short Bs[3][GBN2 * BK];   // 3 x 8 KiB = 48 KB total

    int arow = w * 16 + (l >> 2);
    int aslot = (l & 3) ^ ((arow >> 1) & 3);
    int aslotg = m0 + arow; if (aslotg >= NSLOT) aslotg = NSLOT - 1;
    const short* gA = hbuf + (size_t)aslotg * hlen + aslot * 8;
    int brow = w * 16 + (l >> 2);
    int bslot = (l & 3) ^ ((brow >> 1) & 3);
    const short* gB = w2t + ((size_t)e * DDIM + (size_t)(n0 + brow)) * HDIM + h0 + bslot * 8;

    int l15 = l & 15, kq = l >> 4;
    int aoff[4], boff[2];
#pragma unroll
    for (int mi = 0; mi < 4; ++mi) {
        int R = (w >> 2) * 64 + mi * 16 + l15;
        aoff[mi] = R * BK + ((kq ^ ((R >> 1) & 3)) * 8);
    }
#pragma unroll
    for (int ni = 0; ni < 2; ++ni) {
        int S = (w & 3) * 32 + ni * 16 + l15;
        boff[ni] = S * BK + ((kq ^ ((S >> 1) & 3)) * 8);
    }

    f32x4 vzero = {0.0f, 0.0f, 0.0f, 0.0f};
    f32x4 acc[4][2];
#pragma unroll
    for (int i = 0; i < 4; ++i)
#pragma unroll
        for (int j = 0; j < 2; ++j) acc[i][j] = vzero;

#define STAGE2(T, B) {                                            \
        gload16(gA + (T) * BK, &As[B][w * 512]);                  \
        gload16(gB + (T) * BK, &Bs[B][w * 512]); }

    const int nt = hlen / BK;          // 64 at hlen=2048
    STAGE2(0, 0);
    STAGE2(1, 1);
    int cb = 0, sb = 2;
#pragma unroll 1
    for (int t = 0; t < nt; ++t) {
        if (t < nt - 1) asm volatile("s_waitcnt vmcnt(2)" ::: "memory");
        else            asm volatile("s_waitcnt vmcnt(0)" ::: "memory");
        __builtin_amdgcn_s_barrier();
        __builtin_amdgcn_sched_barrier(0);
        if (t + 2 < nt) STAGE2(t + 2, sb);
        const short* Ab = &As[cb][0];
        const short* Bb = &Bs[cb][0];
        short8 af[4], bv[2];
#pragma unroll
        for (int mi = 0; mi < 4; ++mi) af[mi] = *(const short8*)(Ab + aoff[mi]);
#pragma unroll
        for (int ni = 0; ni < 2; ++ni) bv[ni] = *(const short8*)(Bb + boff[ni]);
        __builtin_amdgcn_s_setprio(1);
#pragma unroll
        for (int mi = 0; mi < 4; ++mi)
#pragma unroll
            for (int ni = 0; ni < 2; ++ni)
                acc[mi][ni] = __builtin_amdgcn_mfma_f32_16x16x32_bf16(
                    af[mi], bv[ni], acc[mi][ni], 0, 0, 0);
        __builtin_amdgcn_s_setprio(0);
        cb = (cb == 2) ? 0 : cb + 1;
        sb = (sb == 2) ? 0 : sb + 1;
    }
#undef STAGE2

    int crow = (w >> 2) * 64 + (kq << 2);
    int ccol = (w & 3) * 32 + l15;
#pragma unroll
    for (int mi = 0; mi < 4; ++mi) {
#pragma unroll
        for (int ni = 0; ni < 2; ++ni) {
            int col = ccol + ni * 16;
            float bias = (h0 == 0) ? b2[e * DDIM + n0 + col] : 0.0f;
#pragma unroll
            for (int j = 0; j < 4; ++j) {
                int row = crow + mi * 16 + j;
                if (row < rows) {
                    float v = acc[mi][ni][j] + bias;
                    if (mode == 0) {  // full-K path: single bf16 write by slot
                        ybuf[(size_t)(m0 + row) * DDIM + n0 + col] = f2bf(v);
                    } else {          // atomic path: token/weight from global (L2)
                        int tokr = list_tok[m0 + row];
                        float wr = list_w[m0 + row];
                        atomicAdd(&out[(size_t)tokr * DDIM + n0 + col], wr * v);
                    }
                }
            }
        }
    }
}

// out[t] = w0*ybuf[pos0] + w1*ybuf[pos1]  (ybuf bf16, 8 cols/thread)
__global__ __launch_bounds__(256) void combine_kernel(
    const short* __restrict__ ybuf, const int* __restrict__ pos_tk,
    const float* __restrict__ tok_w, float* __restrict__ out)
{
    int i = blockIdx.x * 256 + threadIdx.x;   // over T_TOK * 64 units
    int t = i >> 6, c = (i & 63) * 8;
    float w0 = tok_w[2 * t], w1 = tok_w[2 * t + 1];
    int p0 = pos_tk[2 * t], p1 = pos_tk[2 * t + 1];
    short8 a = *(const short8*)(ybuf + (size_t)p0 * DDIM + c);
    short8 b = *(const short8*)(ybuf + (size_t)p1 * DDIM + c);
    float4 o0, o1;
    float* op = (float*)&o0;
#pragma unroll
    for (int j = 0; j < 4; ++j) op[j] = w0 * bf2f(a[j]) + w1 * bf2f(b[j]);
    float* op1 = (float*)&o1;
#pragma unroll
    for (int j = 0; j < 4; ++j) op1[j] = w0 * bf2f(a[4 + j]) + w1 * bf2f(b[4 + j]);
    float4* ob = (float4*)(out + (size_t)t * DDIM + c);
    ob[0] = o0;
    ob[1] = o1;
}

// ---------------- launch ----------------

extern "C" void kernel_launch(void* const* d_in, const int* in_sizes, int n_in,
                              void* d_out, int out_size, void* d_ws, size_t ws_size,
                              hipStream_t stream)
{
    const float* x  = (const float*)d_in[0];
    const float* wg = (const float*)d_in[1];
    const float* bg = (const float*)d_in[2];
    const float* w1 = (const float*)d_in[3];
    const float* b1 = (const float*)d_in[4];
    const float* w2 = (const float*)d_in[5];
    const float* b2 = (const float*)d_in[6];
    float* out = (float*)d_out;

    char* p = (char*)d_ws;
    int* offs     = (int*)(p + 128);            // 32 ints
    int* tile_e   = (int*)(p + 256);            // 512 ints
    int* tile_m0  = (int*)(p + 2304);           // 512 ints
    int* bhist    = (int*)(p + 8192);           // 8 KiB
    int* bbase    = (int*)(p + 16384);          // 8 KiB
    int* tok_e    = (int*)(p + 32768);          // 128 KiB
    float* tok_w  = (float*)(p + 32768 + 131072);
    int* list_tok = (int*)(p + 32768 + 262144);
    float* list_w = (float*)(p + 32768 + 393216);
    int* pos_tk   = (int*)(p + 32768 + 524288);
    short* xbf    = (short*)(p + 32768 + 655360);             // 16 MiB
    short* w1t    = xbf + (size_t)T_TOK * DDIM;               // 32 MiB
    short* w2t    = w1t + (size_t)NEXP * DDIM * HDIM;         // 32 MiB
    char* after   = (char*)(w2t + (size_t)NEXP * DDIM * HDIM);
    size_t fixed  = (size_t)(after - p);

    // mode 0: full-K gemm2 + bf16 ybuf + combine (needs hbuf 134 MB + ybuf 33.5 MB)
    // mode 1 fallback: h-chunked gemm2 with atomic out accumulate.
    int mode, hlen = HDIM;
    if (fixed + (size_t)NSLOT * DDIM * 2 + (size_t)NSLOT * HDIM * 2 <= ws_size) {
        mode = 0;
    } else {
        mode = 1;
        hlen = 0;
        for (int hl = HDIM; hl >= 256; hl >>= 1)
            if (fixed + (size_t)NSLOT * hl * 2 <= ws_size) { hlen = hl; break; }
    }
    short* ybuf = (short*)after;
    short* hbuf = (mode == 0) ? (short*)(after + (size_t)NSLOT * DDIM * 2) : (short*)after;

    if (!hlen) { hipMemsetAsync(d_out, 0, (size_t)out_size * sizeof(float), stream); return; }
    if (mode == 1) hipMemsetAsync(d_out, 0, (size_t)out_size * sizeof(float), stream);

    gate_kernel<<<T_TOK / 4, 256, 0, stream>>>(x, wg, bg, tok_e, tok_w, xbf);
    hist_kernel<<<NHB, 256, 0, stream>>>(tok_e, bhist);
    scan_kernel<<<1, 64, 0, stream>>>(bhist, offs, bbase, tile_e, tile_m0);
    scatter_kernel<<<NHB, 256, 0, stream>>>(tok_e, tok_w, bbase, list_tok, list_w, pos_tk);
    wtrans_kernel<<<dim3(HDIM / 32, DDIM / 32, NEXP), 256, 0, stream>>>(w1, w1t, DDIM, HDIM);
    wtrans_kernel<<<dim3(DDIM / 32, HDIM / 32, NEXP), 256, 0, stream>>>(w2, w2t, HDIM, DDIM);

    // single slice; tile-major XCD decode keeps a tile's chunks adjacent.
    for (int h0 = 0; h0 < HDIM; h0 += hlen) {
        for (int t0 = 0; t0 < MAXTILE; t0 += TSLICE) {
            int tc = MAXTILE - t0; if (tc > TSLICE) tc = TSLICE;
            gemm1_kernel<<<(hlen / GBN1) * tc, 512, 0, stream>>>(
                xbf, w1t, b1, offs, tile_e, tile_m0, list_tok, hbuf, h0, hlen, t0, tc);
            gemm2_kernel<<<(DDIM / GBN2) * tc, 512, 0, stream>>>(
                hbuf, w2t, b2, offs, tile_e, tile_m0, list_tok, list_w,
                ybuf, out, h0, hlen, mode, t0, tc);
        }
    }
    if (mode == 0)
        combine_kernel<<<T_TOK * 64 / 256, 256, 0, stream>>>(ybuf, pos_tk, tok_w, out);
}

// Round 20
// 336.994 us; speedup vs baseline: 1.1378x; 1.0608x over previous
//
#include <hip/hip_runtime.h>
#include <hip/hip_bf16.h>

// MoE: B=4,S=4096,D=512,E=16,H=2048,top-2. T=16384 tokens, 32768 slots.
#define T_TOK 16384
#define DDIM  512
#define NEXP  16
#define HDIM  2048
#define NSLOT (T_TOK * 2)
#define NHB   128         // histogram blocks: NSLOT / 256

#define GBM 128           // gemm tile M (matches tile table)
#define GBN1 128          // gemm1 tile N
#define GBN2 128          // gemm2 tile N
#define BK  32            // gemm K-step
#define MAXTILE 272       // max m-tiles: 32768/128 + 16
#define TSLICE  272       // single slice (r16: slicing cost > its L3 benefit)

typedef __attribute__((ext_vector_type(8))) short short8;   // 8 x bf16
typedef __attribute__((ext_vector_type(4))) short short4v;
typedef __attribute__((ext_vector_type(4))) float f32x4;

__device__ inline short f2bf(float f) {
    __hip_bfloat16 h = __float2bfloat16(f);
    return *reinterpret_cast<short*>(&h);
}
__device__ inline float bf2f(short s) {
    unsigned u = ((unsigned)(unsigned short)s) << 16;
    union { unsigned u; float f; } c; c.u = u; return c.f;
}
// A&S 7.1.26 erf: |abs err| < 1.5e-7 (<< bf16 rounding of hbuf). ~14 VALU ops.
__device__ inline float erf_fast(float x) {
    float ax = fabsf(x);
    float t = 1.0f / fmaf(0.3275911f, ax, 1.0f);
    float p = fmaf(fmaf(fmaf(fmaf(1.061405429f, t, -1.453152027f), t,
                  1.421413741f), t, -0.284496736f), t, 0.254829592f) * t;
    float r = 1.0f - p * __expf(-ax * ax);
    return copysignf(r, x);
}
__device__ inline float geluf(float v) {   // exact-form gelu via fast erf
    return 0.5f * v * (1.0f + erf_fast(v * 0.70710678118654752440f));
}
// async global->LDS, 16B per lane. LDS dest = WAVE-UNIFORM base + lane*16.
__device__ inline void gload16(const void* g, void* l) {
    __builtin_amdgcn_global_load_lds(
        (const __attribute__((address_space(1))) void*)g,
        (__attribute__((address_space(3))) void*)l, 16, 0, 0);
}
// XCD-aware decode, TILE-MAJOR within each XCD (r19: FETCH 198->52 MB).
// lin%8 = XCD (HW round-robin); a tile's nx chunks temporally adjacent.
__device__ inline void xcd_decode(int lin, int nx, int tc, int& y, int& xn) {
    if ((tc & 7) == 0) {
        int tpx = tc >> 3;
        int k = lin & 7, j = lin >> 3;
        y = k * tpx + j / nx;
        xn = j % nx;
    } else {
        xn = lin % nx;
        y = lin / nx;
    }
}

// ---------------- routing ----------------
// wave-per-token gate: lane (g,q) = (d-quarter, expert). fp64 (tie-robust).
// Also emits xbf (bf16 copy of x): gate touches all of x anyway.
__global__ __launch_bounds__(256) void gate_kernel(
    const float* __restrict__ x, const float* __restrict__ wg,
    const float* __restrict__ bg, int* __restrict__ tok_e,
    float* __restrict__ tok_w, short* __restrict__ xbf)
{
    int wv = threadIdx.x >> 6, lane = threadIdx.x & 63;
    int t = blockIdx.x * 4 + wv;
    int g = lane >> 4, q = lane & 15;
    const float* xr = x + (size_t)t * DDIM + g * 128;
    const float* wr = wg + (size_t)g * 128 * NEXP + q;
    double a0 = 0, a1 = 0, a2 = 0, a3 = 0;
#pragma unroll
    for (int c = 0; c < 8; ++c) {
        float4 v0 = ((const float4*)xr)[c * 4 + 0];
        float4 v1 = ((const float4*)xr)[c * 4 + 1];
        float4 v2 = ((const float4*)xr)[c * 4 + 2];
        float4 v3 = ((const float4*)xr)[c * 4 + 3];
        const float* wp = wr + c * 16 * NEXP;
        a0 += (double)v0.x * (double)wp[0 * NEXP];
        a1 += (double)v0.y * (double)wp[1 * NEXP];
        a2 += (double)v0.z * (double)wp[2 * NEXP];
        a3 += (double)v0.w * (double)wp[3 * NEXP];
        a0 += (double)v1.x * (double)wp[4 * NEXP];
        a1 += (double)v1.y * (double)wp[5 * NEXP];
        a2 += (double)v1.z * (double)wp[6 * NEXP];
        a3 += (double)v1.w * (double)wp[7 * NEXP];
        a0 += (double)v2.x * (double)wp[8 * NEXP];
        a1 += (double)v2.y * (double)wp[9 * NEXP];
        a2 += (double)v2.z * (double)wp[10 * NEXP];
        a3 += (double)v2.w * (double)wp[11 * NEXP];
        a0 += (double)v3.x * (double)wp[12 * NEXP];
        a1 += (double)v3.y * (double)wp[13 * NEXP];
        a2 += (double)v3.z * (double)wp[14 * NEXP];
        a3 += (double)v3.w * (double)wp[15 * NEXP];
    }
    double a = ((a0 + a1) + (a2 + a3));
    a += __shfl_xor(a, 16, 64);
    a += __shfl_xor(a, 32, 64);
    a += (double)bg[q];
    double v0 = a; int i0 = q;
#pragma unroll
    for (int s = 1; s < 16; s <<= 1) {
        double ov = __shfl_xor(v0, s, 64);
        int oi = __shfl_xor(i0, s, 64);
        if (ov > v0 || (ov == v0 && oi < i0)) { v0 = ov; i0 = oi; }
    }
    double m2 = (q == i0) ? -1e300 : a;
    double v1 = m2; int i1 = q;
#pragma unroll
    for (int s = 1; s < 16; s <<= 1) {
        double ov = __shfl_xor(v1, s, 64);
        int oi = __shfl_xor(i1, s, 64);
        if (ov > v1 || (ov == v1 && oi < i1)) { v1 = ov; i1 = oi; }
    }
    if (lane == 0) {
        float ex = expf((float)(v1 - v0));      // <= 1
        float w0 = 1.0f / (1.0f + ex);
        tok_e[2 * t] = i0; tok_e[2 * t + 1] = i1;
        tok_w[2 * t] = w0; tok_w[2 * t + 1] = ex * w0;
    }
    // x -> bf16 (this wave's token, 8 elems/lane; x rows are L1-hot)
    {
        const float4* xs = (const float4*)(x + (size_t)t * DDIM + lane * 8);
        float4 u0 = xs[0], u1 = xs[1];
        short8 o;
        o[0] = f2bf(u0.x); o[1] = f2bf(u0.y); o[2] = f2bf(u0.z); o[3] = f2bf(u0.w);
        o[4] = f2bf(u1.x); o[5] = f2bf(u1.y); o[6] = f2bf(u1.z); o[7] = f2bf(u1.w);
        *(short8*)(xbf + (size_t)t * DDIM + lane * 8) = o;
    }
}

// per-block expert histogram (LDS atomics only)
__global__ __launch_bounds__(256) void hist_kernel(
    const int* __restrict__ tok_e, int* __restrict__ bhist)
{
    __shared__ int h[NEXP];
    if (threadIdx.x < NEXP) h[threadIdx.x] = 0;
    __syncthreads();
    atomicAdd(&h[tok_e[blockIdx.x * 256 + threadIdx.x]], 1);
    __syncthreads();
    if (threadIdx.x < NEXP) bhist[blockIdx.x * NEXP + threadIdx.x] = h[threadIdx.x];
}

// offs[0..16] = exclusive scan; offs[17] = ntiles; bbase[b][e] = scatter base.
__global__ void scan_kernel(const int* __restrict__ bhist, int* __restrict__ offs,
                            int* __restrict__ bbase, int* __restrict__ tile_e,
                            int* __restrict__ tile_m0)
{
    int tid = threadIdx.x;
    __shared__ int tot[NEXP];
    if (tid < NEXP) {
        int s = 0;
        for (int b = 0; b < NHB; ++b) s += bhist[b * NEXP + tid];
        tot[tid] = s;
    }
    __syncthreads();
    if (tid == 0) {
        int run = 0;
        for (int e = 0; e < NEXP; ++e) { offs[e] = run; run += tot[e]; }
        offs[NEXP] = run;   // == NSLOT
        int nt = 0;
        for (int e = 0; e < NEXP; ++e)
            for (int m = offs[e]; m < offs[e + 1]; m += GBM) {
                tile_e[nt] = e; tile_m0[nt] = m; ++nt;
            }
        offs[17] = nt;
    }
    __syncthreads();
    if (tid < NEXP) {
        int run = offs[tid];
        for (int b = 0; b < NHB; ++b) {
            bbase[b * NEXP + tid] = run;
            run += bhist[b * NEXP + tid];
        }
    }
}

// local rank via LDS atomic + precomputed block base
__global__ __launch_bounds__(256) void scatter_kernel(
    const int* __restrict__ tok_e, const float* __restrict__ tok_w,
    const int* __restrict__ bbase, int* __restrict__ list_tok,
    float* __restrict__ list_w, int* __restrict__ pos_tk)
{
    __shared__ int h[NEXP];
    if (threadIdx.x < NEXP) h[threadIdx.x] = 0;
    __syncthreads();
    int s = blockIdx.x * 256 + threadIdx.x;
    int e = tok_e[s];
    int r = atomicAdd(&h[e], 1);
    int pos = bbase[blockIdx.x * NEXP + e] + r;
    list_tok[pos] = s >> 1;
    list_w[pos] = tok_w[s];
    pos_tk[s] = pos;
}

// ---------------- pre-conversion ----------------

// transpose one [R][C] fp32 matrix per blockIdx.z into [C][R] bf16
__global__ void wtrans_kernel(const float* __restrict__ src, short* __restrict__ dst, int R, int C)
{
    __shared__ float t[32][33];
    int c0 = blockIdx.x * 32, r0 = blockIdx.y * 32;
    const float* s = src + (size_t)blockIdx.z * R * C;
    short* d = dst + (size_t)blockIdx.z * R * C;
    int cc = threadIdx.x & 31, rr = threadIdx.x >> 5;
#pragma unroll
    for (int pp = 0; pp < 4; ++pp)
        t[rr + pp * 8][cc] = s[(size_t)(r0 + rr + pp * 8) * C + c0 + cc];
    __syncthreads();
#pragma unroll
    for (int pp = 0; pp < 4; ++pp) {
        int c = rr + pp * 8;
        d[(size_t)(c0 + c) * R + r0 + cc] = f2bf(t[cc][c]);
    }
}

// ---------------- expert GEMMs: 3-buf counted-vmcnt, 128x128 tiles ----------
// r20: K-loop hand-unrolled x3 with STATIC buffer indices. r19 PMC showed
// VALUBusy 56% > MFMA 20% - the runtime cb/sb modulo rotation forced
// cmp+cndmask chains and per-step re-derivation of 6 LDS frag addresses.
// Static CB folds (CB+2)%3 and lets the compiler precompute all 3 address
// sets once. Schedule semantics identical (counted vmcnt, 1 barrier/step).

__global__ __launch_bounds__(512) void gemm1_kernel(
    const short* __restrict__ xbf, const short* __restrict__ w1t,
    const float* __restrict__ b1, const int* __restrict__ offs,
    const int* __restrict__ tile_e, const int* __restrict__ tile_m0,
    const int* __restrict__ list_tok, short* __restrict__ hbuf,
    int h0, int hlen, int t0, int tc)
{
    int ty, xn;
    xcd_decode((int)blockIdx.x, hlen / GBN1, tc, ty, xn);
    int tb = t0 + ty;
    if (tb >= offs[17]) return;
    int e = tile_e[tb], m0 = tile_m0[tb];
    int rows = offs[e + 1] - m0; if (rows > GBM) rows = GBM;
    int n0 = xn * GBN1;
    int tid = threadIdx.x, l = tid & 63, w = tid >> 6;

    __shared__ __align__(16) short As[3][GBM * BK];    // 3 x 8 KiB
    __shared__ __align__(16) short Bs[3][GBN1 * BK];   // 3 x 8 KiB = 48 KB

    int arow = w * 16 + (l >> 2);
    int aslot = (l & 3) ^ ((arow >> 1) & 3);
    int tok = list_tok[m0 + (arow < rows ? arow : rows - 1)];
    const short* gA = xbf + (size_t)tok * DDIM + aslot * 8;
    int brow = w * 16 + (l >> 2);
    int bslot = (l & 3) ^ ((brow >> 1) & 3);
    const short* gB = w1t + ((size_t)e * HDIM + (size_t)(h0 + n0 + brow)) * DDIM + bslot * 8;

    int l15 = l & 15, kq = l >> 4;
    int aoff[4], boff[2];
#pragma unroll
    for (int mi = 0; mi < 4; ++mi) {
        int R = (w >> 2) * 64 + mi * 16 + l15;
        aoff[mi] = R * BK + ((kq ^ ((R >> 1) & 3)) * 8);
    }
#pragma unroll
    for (int ni = 0; ni < 2; ++ni) {
        int S = (w & 3) * 32 + ni * 16 + l15;
        boff[ni] = S * BK + ((kq ^ ((S >> 1) & 3)) * 8);
    }

    f32x4 vzero = {0.0f, 0.0f, 0.0f, 0.0f};
    f32x4 acc[4][2];
#pragma unroll
    for (int i = 0; i < 4; ++i)
#pragma unroll
        for (int j = 0; j < 2; ++j) acc[i][j] = vzero;

#define STAGE1(T, B) {                                            \
        gload16(gA + (T) * BK, &As[B][w * 512]);                  \
        gload16(gB + (T) * BK, &Bs[B][w * 512]); }

#define K1(T, CB, DOST, LAST) {                                   \
        if (LAST) asm volatile("s_waitcnt vmcnt(0)" ::: "memory");\
        else      asm volatile("s_waitcnt vmcnt(2)" ::: "memory");\
        __builtin_amdgcn_s_barrier();                             \
        __builtin_amdgcn_sched_barrier(0);                        \
        if (DOST) STAGE1((T) + 2, ((CB) + 2) % 3);                \
        short8 af[4], bv[2];                                      \
        _Pragma("unroll")                                         \
        for (int mi = 0; mi < 4; ++mi)                            \
            af[mi] = *(const short8*)(&As[CB][0] + aoff[mi]);     \
        _Pragma("unroll")                                         \
        for (int ni = 0; ni < 2; ++ni)                            \
            bv[ni] = *(const short8*)(&Bs[CB][0] + boff[ni]);     \
        __builtin_amdgcn_s_setprio(1);                            \
        _Pragma("unroll")                                         \
        for (int mi = 0; mi < 4; ++mi)                            \
            _Pragma("unroll")                                     \
            for (int ni = 0; ni < 2; ++ni)                        \
                acc[mi][ni] = __builtin_amdgcn_mfma_f32_16x16x32_bf16( \
                    af[mi], bv[ni], acc[mi][ni], 0, 0, 0);        \
        __builtin_amdgcn_s_setprio(0);                            \
    }

    // nt = 16 K-steps; buffers cycle period 3 -> 4 full groups + 4-step tail
    STAGE1(0, 0);
    STAGE1(1, 1);
#pragma unroll 1
    for (int g = 0; g < 4; ++g) {        // t = 3g..3g+2 (0..11), all stage
        int t3 = 3 * g;
        K1(t3 + 0, 0, 1, 0);
        K1(t3 + 1, 1, 1, 0);
        K1(t3 + 2, 2, 1, 0);
    }
    K1(12, 0, 1, 0);
    K1(13, 1, 1, 0);
    K1(14, 2, 0, 0);
    K1(15, 0, 0, 1);
#undef K1
#undef STAGE1

    int crow = (w >> 2) * 64 + (kq << 2);
    int ccol = (w & 3) * 32 + l15;
#pragma unroll
    for (int mi = 0; mi < 4; ++mi) {
#pragma unroll
        for (int ni = 0; ni < 2; ++ni) {
            int col = ccol + ni * 16;
            float bias = b1[e * HDIM + h0 + n0 + col];
#pragma unroll
            for (int j = 0; j < 4; ++j) {
                int row = crow + mi * 16 + j;
                if (row < rows) {
                    float v = acc[mi][ni][j] + bias;
                    hbuf[(size_t)(m0 + row) * hlen + (n0 + col)] = f2bf(geluf(v));
                }
            }
        }
    }
}

__global__ __launch_bounds__(512) void gemm2_kernel(
    const short* __restrict__ hbuf, const short* __restrict__ w2t,
    const float* __restrict__ b2, const int* __restrict__ offs,
    const int* __restrict__ tile_e, const int* __restrict__ tile_m0,
    const int* __restrict__ list_tok, const float* __restrict__ list_w,
    short* __restrict__ ybuf, float* __restrict__ out,
    int h0, int hlen, int mode, int t0, int tc)
{
    int ty, xn;
    xcd_decode((int)blockIdx.x, DDIM / GBN2, tc, ty, xn);
    int tb = t0 + ty;
    if (tb >= offs[17]) return;
    int e = tile_e[tb], m0 = tile_m0[tb];
    int rows = offs[e + 1] - m0; if (rows > GBM) rows = GBM;
    int n0 = xn * GBN2;                  // output d coordinate
    int tid = threadIdx.x, l = tid & 63, w = tid >> 6;

    __shared__ __align__(16) short As[3][GBM * BK];    // 3 x 8 KiB
    __shared__ __align__(16) short Bs[3][GBN2 * BK];   // 3 x 8 KiB = 48 KB total

    int arow = w * 16 + (l >> 2);
    int aslot = (l & 3) ^ ((arow >> 1) & 3);
    int aslotg = m0 + arow; if (aslotg >= NSLOT) aslotg = NSLOT - 1;
    const short* gA = hbuf + (size_t)aslotg * hlen + aslot * 8;
    int brow = w * 16 + (l >> 2);
    int bslot = (l & 3) ^ ((brow >> 1) & 3);
    const short* gB = w2t + ((size_t)e * DDIM + (size_t)(n0 + brow)) * HDIM + h0 + bslot * 8;

    int l15 = l & 15, kq = l >> 4;
    int aoff[4], boff[2];
#pragma unroll
    for (int mi = 0; mi < 4; ++mi) {
        int R = (w >> 2) * 64 + mi * 16 + l15;
        aoff[mi] = R * BK + ((kq ^ ((R >> 1) & 3)) * 8);
    }
#pragma unroll
    for (int ni = 0; ni < 2; ++ni) {
        int S = (w & 3) * 32 + ni * 16 + l15;
        boff[ni] = S * BK + ((kq ^ ((S >> 1) & 3)) * 8);
    }

    f32x4 vzero = {0.0f, 0.0f, 0.0f, 0.0f};
    f32x4 acc[4][2];
#pragma unroll
    for (int i = 0; i < 4; ++i)
#pragma unroll
        for (int j = 0; j < 2; ++j) acc[i][j] = vzero;

#define STAGE2(T, B) {                                            \
        gload16(gA + (T) * BK, &As[B][w * 512]);                  \
        gload16(gB + (T) * BK, &Bs[B][w * 512]); }

#define K2(T, CB, DOST, LAST) {                                   \
        if (LAST) asm volatile("s_waitcnt vmcnt(0)" ::: "memory");\
        else      asm volatile("s_waitcnt vmcnt(2)" ::: "memory");\
        __builtin_amdgcn_s_barrier();                             \
        __builtin_amdgcn_sched_barrier(0);                        \
        if (DOST) STAGE2((T) + 2, ((CB) + 2) % 3);                \
        short8 af[4], bv[2];                                      \
        _Pragma("unroll")                                         \
        for (int mi = 0; mi < 4; ++mi)                            \
            af[mi] = *(const short8*)(&As[CB][0] + aoff[mi]);     \
        _Pragma("unroll")                                         \
        for (int ni = 0; ni < 2; ++ni)                            \
            bv[ni] = *(const short8*)(&Bs[CB][0] + boff[ni]);     \
        __builtin_amdgcn_s_setprio(1);                            \
        _Pragma("unroll")                                         \
        for (int mi = 0; mi < 4; ++mi)                            \
            _Pragma("unroll")                                     \
            for (int ni = 0; ni < 2; ++ni)                        \
                acc[mi][ni] = __builtin_amdgcn_mfma_f32_16x16x32_bf16( \
                    af[mi], bv[ni], acc[mi][ni], 0, 0, 0);        \
        __builtin_amdgcn_s_setprio(0);                            \
    }

    // nt = 64 K-steps: 20 full groups (t=0..59) + 4-step tail
    STAGE2(0, 0);
    STAGE2(1, 1);
#pragma unroll 1
    for (int g = 0; g < 20; ++g) {
        int t3 = 3 * g;
        K2(t3 + 0, 0, 1, 0);
        K2(t3 + 1, 1, 1, 0);
        K2(t3 + 2, 2, 1, 0);
    }
    K2(60, 0, 1, 0);
    K2(61, 1, 1, 0);
    K2(62, 2, 0, 0);
    K2(63, 0, 0, 1);
#undef K2
#undef STAGE2

    int crow = (w >> 2) * 64 + (kq << 2);
    int ccol = (w & 3) * 32 + l15;
#pragma unroll
    for (int mi = 0; mi < 4; ++mi) {
#pragma unroll
        for (int ni = 0; ni < 2; ++ni) {
            int col = ccol + ni * 16;
            float bias = (h0 == 0) ? b2[e * DDIM + n0 + col] : 0.0f;
#pragma unroll
            for (int j = 0; j < 4; ++j) {
                int row = crow + mi * 16 + j;
                if (row < rows) {
                    float v = acc[mi][ni][j] + bias;
                    if (mode == 0) {  // full-K path: single bf16 write by slot
                        ybuf[(size_t)(m0 + row) * DDIM + n0 + col] = f2bf(v);
                    } else {          // atomic path: token/weight from global (L2)
                        int tokr = list_tok[m0 + row];
                        float wr = list_w[m0 + row];
                        atomicAdd(&out[(size_t)tokr * DDIM + n0 + col], wr * v);
                    }
                }
            }
        }
    }
}

// out[t] = w0*ybuf[pos0] + w1*ybuf[pos1]  (ybuf bf16, 8 cols/thread)
__global__ __launch_bounds__(256) void combine_kernel(
    const short* __restrict__ ybuf, const int* __restrict__ pos_tk,
    const float* __restrict__ tok_w, float* __restrict__ out)
{
    int i = blockIdx.x * 256 + threadIdx.x;   // over T_TOK * 64 units
    int t = i >> 6, c = (i & 63) * 8;
    float w0 = tok_w[2 * t], w1 = tok_w[2 * t + 1];
    int p0 = pos_tk[2 * t], p1 = pos_tk[2 * t + 1];
    short8 a = *(const short8*)(ybuf + (size_t)p0 * DDIM + c);
    short8 b = *(const short8*)(ybuf + (size_t)p1 * DDIM + c);
    float4 o0, o1;
    float* op = (float*)&o0;
#pragma unroll
    for (int j = 0; j < 4; ++j) op[j] = w0 * bf2f(a[j]) + w1 * bf2f(b[j]);
    float* op1 = (float*)&o1;
#pragma unroll
    for (int j = 0; j < 4; ++j) op1[j] = w0 * bf2f(a[4 + j]) + w1 * bf2f(b[4 + j]);
    float4* ob = (float4*)(out + (size_t)t * DDIM + c);
    ob[0] = o0;
    ob[1] = o1;
}

// ---------------- launch ----------------

extern "C" void kernel_launch(void* const* d_in, const int* in_sizes, int n_in,
                              void* d_out, int out_size, void* d_ws, size_t ws_size,
                              hipStream_t stream)
{
    const float* x  = (const float*)d_in[0];
    const float* wg = (const float*)d_in[1];
    const float* bg = (const float*)d_in[2];
    const float* w1 = (const float*)d_in[3];
    const float* b1 = (const float*)d_in[4];
    const float* w2 = (const float*)d_in[5];
    const float* b2 = (const float*)d_in[6];
    float* out = (float*)d_out;

    char* p = (char*)d_ws;
    int* offs     = (int*)(p + 128);            // 32 ints
    int* tile_e   = (int*)(p + 256);            // 512 ints
    int* tile_m0  = (int*)(p + 2304);           // 512 ints
    int* bhist    = (int*)(p + 8192);           // 8 KiB
    int* bbase    = (int*)(p + 16384);          // 8 KiB
    int* tok_e    = (int*)(p + 32768);          // 128 KiB
    float* tok_w  = (float*)(p + 32768 + 131072);
    int* list_tok = (int*)(p + 32768 + 262144);
    float* list_w = (float*)(p + 32768 + 393216);
    int* pos_tk   = (int*)(p + 32768 + 524288);
    short* xbf    = (short*)(p + 32768 + 655360);             // 16 MiB
    short* w1t    = xbf + (size_t)T_TOK * DDIM;               // 32 MiB
    short* w2t    = w1t + (size_t)NEXP * DDIM * HDIM;         // 32 MiB
    char* after   = (char*)(w2t + (size_t)NEXP * DDIM * HDIM);
    size_t fixed  = (size_t)(after - p);

    // mode 0: full-K gemm2 + bf16 ybuf + combine (needs hbuf 134 MB + ybuf 33.5 MB)
    // mode 1 fallback: h-chunked gemm2 with atomic out accumulate.
    int mode, hlen = HDIM;
    if (fixed + (size_t)NSLOT * DDIM * 2 + (size_t)NSLOT * HDIM * 2 <= ws_size) {
        mode = 0;
    } else {
        mode = 1;
        hlen = 0;
        for (int hl = HDIM; hl >= 256; hl >>= 1)
            if (fixed + (size_t)NSLOT * hl * 2 <= ws_size) { hlen = hl; break; }
    }
    short* ybuf = (short*)after;
    short* hbuf = (mode == 0) ? (short*)(after + (size_t)NSLOT * DDIM * 2) : (short*)after;

    if (!hlen) { hipMemsetAsync(d_out, 0, (size_t)out_size * sizeof(float), stream); return; }
    if (mode == 1) hipMemsetAsync(d_out, 0, (size_t)out_size * sizeof(float), stream);

    gate_kernel<<<T_TOK / 4, 256, 0, stream>>>(x, wg, bg, tok_e, tok_w, xbf);
    hist_kernel<<<NHB, 256, 0, stream>>>(tok_e, bhist);
    scan_kernel<<<1, 64, 0, stream>>>(bhist, offs, bbase, tile_e, tile_m0);
    scatter_kernel<<<NHB, 256, 0, stream>>>(tok_e, tok_w, bbase, list_tok, list_w, pos_tk);
    wtrans_kernel<<<dim3(HDIM / 32, DDIM / 32, NEXP), 256, 0, stream>>>(w1, w1t, DDIM, HDIM);
    wtrans_kernel<<<dim3(DDIM / 32, HDIM / 32, NEXP), 256, 0, stream>>>(w2, w2t, HDIM, DDIM);

    // single slice; tile-major XCD decode keeps a tile's chunks adjacent.
    for (int h0 = 0; h0 < HDIM; h0 += hlen) {
        for (int t0 = 0; t0 < MAXTILE; t0 += TSLICE) {
            int tc = MAXTILE - t0; if (tc > TSLICE) tc = TSLICE;
            gemm1_kernel<<<(hlen / GBN1) * tc, 512, 0, stream>>>(
                xbf, w1t, b1, offs, tile_e, tile_m0, list_tok, hbuf, h0, hlen, t0, tc);
            gemm2_kernel<<<(DDIM / GBN2) * tc, 512, 0, stream>>>(
                hbuf, w2t, b2, offs, tile_e, tile_m0, list_tok, list_w,
                ybuf, out, h0, hlen, mode, t0, tc);
        }
    }
    if (mode == 0)
        combine_kernel<<<T_TOK * 64 / 256, 256, 0, stream>>>(ybuf, pos_tk, tok_w, out);
}

// Round 21
// 336.480 us; speedup vs baseline: 1.1396x; 1.0015x over previous
//
#include <hip/hip_runtime.h>
#include <hip/hip_bf16.h>

// MoE: B=4,S=4096,D=512,E=16,H=2048,top-2. T=16384 tokens, 32768 slots.
#define T_TOK 16384
#define DDIM  512
#define NEXP  16
#define HDIM  2048
#define NSLOT (T_TOK * 2)
#define NHB   128         // histogram blocks: NSLOT / 256

#define GBM 128           // gemm tile M (matches tile table)
#define GBN1 128          // gemm1 tile N
#define GBN2 128          // gemm2 tile N
#define BK  32            // gemm K-step
#define MAXTILE 272       // max m-tiles: 32768/128 + 16
#define TSLICE  272       // single slice (r16: slicing cost > its L3 benefit)

typedef __attribute__((ext_vector_type(8))) short short8;   // 8 x bf16
typedef __attribute__((ext_vector_type(4))) short short4v;
typedef __attribute__((ext_vector_type(4))) float f32x4;

__device__ inline short f2bf(float f) {
    __hip_bfloat16 h = __float2bfloat16(f);
    return *reinterpret_cast<short*>(&h);
}
__device__ inline float bf2f(short s) {
    unsigned u = ((unsigned)(unsigned short)s) << 16;
    union { unsigned u; float f; } c; c.u = u; return c.f;
}
// A&S 7.1.26 erf: |abs err| < 1.5e-7 (<< bf16 rounding of hbuf). ~14 VALU ops.
__device__ inline float erf_fast(float x) {
    float ax = fabsf(x);
    float t = 1.0f / fmaf(0.3275911f, ax, 1.0f);
    float p = fmaf(fmaf(fmaf(fmaf(1.061405429f, t, -1.453152027f), t,
                  1.421413741f), t, -0.284496736f), t, 0.254829592f) * t;
    float r = 1.0f - p * __expf(-ax * ax);
    return copysignf(r, x);
}
__device__ inline float geluf(float v) {   // exact-form gelu via fast erf
    return 0.5f * v * (1.0f + erf_fast(v * 0.70710678118654752440f));
}
// async global->LDS, 16B per lane. LDS dest = WAVE-UNIFORM base + lane*16.
__device__ inline void gload16(const void* g, void* l) {
    __builtin_amdgcn_global_load_lds(
        (const __attribute__((address_space(1))) void*)g,
        (__attribute__((address_space(3))) void*)l, 16, 0, 0);
}
// XCD-aware decode, TILE-MAJOR within each XCD (r19: FETCH 198->52 MB).
// lin%8 = XCD (HW round-robin); a tile's nx chunks temporally adjacent.
__device__ inline void xcd_decode(int lin, int nx, int tc, int& y, int& xn) {
    if ((tc & 7) == 0) {
        int tpx = tc >> 3;
        int k = lin & 7, j = lin >> 3;
        y = k * tpx + j / nx;
        xn = j % nx;
    } else {
        xn = lin % nx;
        y = lin / nx;
    }
}

// ---------------- routing ----------------
// wave-per-token gate: lane (g,q) = (d-quarter, expert). fp64 (tie-robust).
// Also emits xbf (bf16 copy of x): gate touches all of x anyway.
__global__ __launch_bounds__(256) void gate_kernel(
    const float* __restrict__ x, const float* __restrict__ wg,
    const float* __restrict__ bg, int* __restrict__ tok_e,
    float* __restrict__ tok_w, short* __restrict__ xbf)
{
    int wv = threadIdx.x >> 6, lane = threadIdx.x & 63;
    int t = blockIdx.x * 4 + wv;
    int g = lane >> 4, q = lane & 15;
    const float* xr = x + (size_t)t * DDIM + g * 128;
    const float* wr = wg + (size_t)g * 128 * NEXP + q;
    double a0 = 0, a1 = 0, a2 = 0, a3 = 0;
#pragma unroll
    for (int c = 0; c < 8; ++c) {
        float4 v0 = ((const float4*)xr)[c * 4 + 0];
        float4 v1 = ((const float4*)xr)[c * 4 + 1];
        float4 v2 = ((const float4*)xr)[c * 4 + 2];
        float4 v3 = ((const float4*)xr)[c * 4 + 3];
        const float* wp = wr + c * 16 * NEXP;
        a0 += (double)v0.x * (double)wp[0 * NEXP];
        a1 += (double)v0.y * (double)wp[1 * NEXP];
        a2 += (double)v0.z * (double)wp[2 * NEXP];
        a3 += (double)v0.w * (double)wp[3 * NEXP];
        a0 += (double)v1.x * (double)wp[4 * NEXP];
        a1 += (double)v1.y * (double)wp[5 * NEXP];
        a2 += (double)v1.z * (double)wp[6 * NEXP];
        a3 += (double)v1.w * (double)wp[7 * NEXP];
        a0 += (double)v2.x * (double)wp[8 * NEXP];
        a1 += (double)v2.y * (double)wp[9 * NEXP];
        a2 += (double)v2.z * (double)wp[10 * NEXP];
        a3 += (double)v2.w * (double)wp[11 * NEXP];
        a0 += (double)v3.x * (double)wp[12 * NEXP];
        a1 += (double)v3.y * (double)wp[13 * NEXP];
        a2 += (double)v3.z * (double)wp[14 * NEXP];
        a3 += (double)v3.w * (double)wp[15 * NEXP];
    }
    double a = ((a0 + a1) + (a2 + a3));
    a += __shfl_xor(a, 16, 64);
    a += __shfl_xor(a, 32, 64);
    a += (double)bg[q];
    double v0 = a; int i0 = q;
#pragma unroll
    for (int s = 1; s < 16; s <<= 1) {
        double ov = __shfl_xor(v0, s, 64);
        int oi = __shfl_xor(i0, s, 64);
        if (ov > v0 || (ov == v0 && oi < i0)) { v0 = ov; i0 = oi; }
    }
    double m2 = (q == i0) ? -1e300 : a;
    double v1 = m2; int i1 = q;
#pragma unroll
    for (int s = 1; s < 16; s <<= 1) {
        double ov = __shfl_xor(v1, s, 64);
        int oi = __shfl_xor(i1, s, 64);
        if (ov > v1 || (ov == v1 && oi < i1)) { v1 = ov; i1 = oi; }
    }
    if (lane == 0) {
        float ex = expf((float)(v1 - v0));      // <= 1
        float w0 = 1.0f / (1.0f + ex);
        tok_e[2 * t] = i0; tok_e[2 * t + 1] = i1;
        tok_w[2 * t] = w0; tok_w[2 * t + 1] = ex * w0;
    }
    // x -> bf16 (this wave's token, 8 elems/lane; x rows are L1-hot)
    {
        const float4* xs = (const float4*)(x + (size_t)t * DDIM + lane * 8);
        float4 u0 = xs[0], u1 = xs[1];
        short8 o;
        o[0] = f2bf(u0.x); o[1] = f2bf(u0.y); o[2] = f2bf(u0.z); o[3] = f2bf(u0.w);
        o[4] = f2bf(u1.x); o[5] = f2bf(u1.y); o[6] = f2bf(u1.z); o[7] = f2bf(u1.w);
        *(short8*)(xbf + (size_t)t * DDIM + lane * 8) = o;
    }
}

// per-block expert histogram (LDS atomics only)
__global__ __launch_bounds__(256) void hist_kernel(
    const int* __restrict__ tok_e, int* __restrict__ bhist)
{
    __shared__ int h[NEXP];
    if (threadIdx.x < NEXP) h[threadIdx.x] = 0;
    __syncthreads();
    atomicAdd(&h[tok_e[blockIdx.x * 256 + threadIdx.x]], 1);
    __syncthreads();
    if (threadIdx.x < NEXP) bhist[blockIdx.x * NEXP + threadIdx.x] = h[threadIdx.x];
}

// offs[0..16] = exclusive scan; offs[17] = ntiles; bbase[b][e] = scatter base.
__global__ void scan_kernel(const int* __restrict__ bhist, int* __restrict__ offs,
                            int* __restrict__ bbase, int* __restrict__ tile_e,
                            int* __restrict__ tile_m0)
{
    int tid = threadIdx.x;
    __shared__ int tot[NEXP];
    if (tid < NEXP) {
        int s = 0;
        for (int b = 0; b < NHB; ++b) s += bhist[b * NEXP + tid];
        tot[tid] = s;
    }
    __syncthreads();
    if (tid == 0) {
        int run = 0;
        for (int e = 0; e < NEXP; ++e) { offs[e] = run; run += tot[e]; }
        offs[NEXP] = run;   // == NSLOT
        int nt = 0;
        for (int e = 0; e < NEXP; ++e)
            for (int m = offs[e]; m < offs[e + 1]; m += GBM) {
                tile_e[nt] = e; tile_m0[nt] = m; ++nt;
            }
        offs[17] = nt;
    }
    __syncthreads();
    if (tid < NEXP) {
        int run = offs[tid];
        for (int b = 0; b < NHB; ++b) {
            bbase[b * NEXP + tid] = run;
            run += bhist[b * NEXP + tid];
        }
    }
}

// local rank via LDS atomic + precomputed block base
__global__ __launch_bounds__(256) void scatter_kernel(
    const int* __restrict__ tok_e, const float* __restrict__ tok_w,
    const int* __restrict__ bbase, int* __restrict__ list_tok,
    float* __restrict__ list_w, int* __restrict__ pos_tk)
{
    __shared__ int h[NEXP];
    if (threadIdx.x < NEXP) h[threadIdx.x] = 0;
    __syncthreads();
    int s = blockIdx.x * 256 + threadIdx.x;
    int e = tok_e[s];
    int r = atomicAdd(&h[e], 1);
    int pos = bbase[blockIdx.x * NEXP + e] + r;
    list_tok[pos] = s >> 1;
    list_w[pos] = tok_w[s];
    pos_tk[s] = pos;
}

// ---------------- pre-conversion ----------------

// transpose one [R][C] fp32 matrix per blockIdx.z into [C][R] bf16.
// r21: 64x64 tiles, float4 reads, short8 writes (8 lanes = 128 B contiguous
// per output row). Old 32x32 version stored 2 B/lane scalar (G13 violation).
__global__ __launch_bounds__(256) void wtrans_kernel(
    const float* __restrict__ src, short* __restrict__ dst, int R, int C)
{
    __shared__ float t[64][65];
    int c0 = blockIdx.x * 64, r0 = blockIdx.y * 64;
    const float* s = src + (size_t)blockIdx.z * R * C;
    short* d = dst + (size_t)blockIdx.z * R * C;
    int cq = threadIdx.x & 15, rr = threadIdx.x >> 4;   // cq: float4-col, rr: row
#pragma unroll
    for (int p = 0; p < 4; ++p) {
        int r = rr + p * 16;
        float4 v = *(const float4*)(s + (size_t)(r0 + r) * C + c0 + cq * 4);
        t[r][cq * 4 + 0] = v.x;
        t[r][cq * 4 + 1] = v.y;
        t[r][cq * 4 + 2] = v.z;
        t[r][cq * 4 + 3] = v.w;
    }
    __syncthreads();
    int uc = threadIdx.x >> 3, ur = threadIdx.x & 7;    // uc: out-row half, ur: 8-col unit
#pragma unroll
    for (int p = 0; p < 2; ++p) {
        int c = uc + p * 32;
        short8 o;
#pragma unroll
        for (int j = 0; j < 8; ++j) o[j] = f2bf(t[ur * 8 + j][c]);
        *(short8*)(d + (size_t)(c0 + c) * R + r0 + ur * 8) = o;
    }
}

// ---------------- expert GEMMs: 3-buf counted-vmcnt, 128x128 tiles ----------
// r20: K-loop hand-unrolled x3 with STATIC buffer indices (VALU bookkeeping
// removed; VGPR 40). Steady vmcnt(2), 1 barrier/K-step, T2 both-sides
// swizzle, tile-major XCD swizzle. 48 KB LDS -> 3 blk/CU.

__global__ __launch_bounds__(512) void gemm1_kernel(
    const short* __restrict__ xbf, const short* __restrict__ w1t,
    const float* __restrict__ b1, const int* __restrict__ offs,
    const int* __restrict__ tile_e, const int* __restrict__ tile_m0,
    const int* __restrict__ list_tok, short* __restrict__ hbuf,
    int h0, int hlen, int t0, int tc)
{
    int ty, xn;
    xcd_decode((int)blockIdx.x, hlen / GBN1, tc, ty, xn);
    int tb = t0 + ty;
    if (tb >= offs[17]) return;
    int e = tile_e[tb], m0 = tile_m0[tb];
    int rows = offs[e + 1] - m0; if (rows > GBM) rows = GBM;
    int n0 = xn * GBN1;
    int tid = threadIdx.x, l = tid & 63, w = tid >> 6;

    __shared__ __align__(16) short As[3][GBM * BK];    // 3 x 8 KiB
    __shared__ __align__(16) short Bs[3][GBN1 * BK];   // 3 x 8 KiB = 48 KB

    int arow = w * 16 + (l >> 2);
    int aslot = (l & 3) ^ ((arow >> 1) & 3);
    int tok = list_tok[m0 + (arow < rows ? arow : rows - 1)];
    const short* gA = xbf + (size_t)tok * DDIM + aslot * 8;
    int brow = w * 16 + (l >> 2);
    int bslot = (l & 3) ^ ((brow >> 1) & 3);
    const short* gB = w1t + ((size_t)e * HDIM + (size_t)(h0 + n0 + brow)) * DDIM + bslot * 8;

    int l15 = l & 15, kq = l >> 4;
    int aoff[4], boff[2];
#pragma unroll
    for (int mi = 0; mi < 4; ++mi) {
        int R = (w >> 2) * 64 + mi * 16 + l15;
        aoff[mi] = R * BK + ((kq ^ ((R >> 1) & 3)) * 8);
    }
#pragma unroll
    for (int ni = 0; ni < 2; ++ni) {
        int S = (w & 3) * 32 + ni * 16 + l15;
        boff[ni] = S * BK + ((kq ^ ((S >> 1) & 3)) * 8);
    }

    f32x4 vzero = {0.0f, 0.0f, 0.0f, 0.0f};
    f32x4 acc[4][2];
#pragma unroll
    for (int i = 0; i < 4; ++i)
#pragma unroll
        for (int j = 0; j < 2; ++j) acc[i][j] = vzero;

#define STAGE1(T, B) {                                            \
        gload16(gA + (T) * BK, &As[B][w * 512]);                  \
        gload16(gB + (T) * BK, &Bs[B][w * 512]); }

#define K1(T, CB, DOST, LAST) {                                   \
        if (LAST) asm volatile("s_waitcnt vmcnt(0)" ::: "memory");\
        else      asm volatile("s_waitcnt vmcnt(2)" ::: "memory");\
        __builtin_amdgcn_s_barrier();                             \
        __builtin_amdgcn_sched_barrier(0);                        \
        if (DOST) STAGE1((T) + 2, ((CB) + 2) % 3);                \
        short8 af[4], bv[2];                                      \
        _Pragma("unroll")                                         \
        for (int mi = 0; mi < 4; ++mi)                            \
            af[mi] = *(const short8*)(&As[CB][0] + aoff[mi]);     \
        _Pragma("unroll")                                         \
        for (int ni = 0; ni < 2; ++ni)                            \
            bv[ni] = *(const short8*)(&Bs[CB][0] + boff[ni]);     \
        __builtin_amdgcn_s_setprio(1);                            \
        _Pragma("unroll")                                         \
        for (int mi = 0; mi < 4; ++mi)                            \
            _Pragma("unroll")                                     \
            for (int ni = 0; ni < 2; ++ni)                        \
                acc[mi][ni] = __builtin_amdgcn_mfma_f32_16x16x32_bf16( \
                    af[mi], bv[ni], acc[mi][ni], 0, 0, 0);        \
        __builtin_amdgcn_s_setprio(0);                            \
    }

    // nt = 16 K-steps; buffers cycle period 3 -> 4 full groups + 4-step tail
    STAGE1(0, 0);
    STAGE1(1, 1);
#pragma unroll 1
    for (int g = 0; g < 4; ++g) {        // t = 3g..3g+2 (0..11), all stage
        int t3 = 3 * g;
        K1(t3 + 0, 0, 1, 0);
        K1(t3 + 1, 1, 1, 0);
        K1(t3 + 2, 2, 1, 0);
    }
    K1(12, 0, 1, 0);
    K1(13, 1, 1, 0);
    K1(14, 2, 0, 0);
    K1(15, 0, 0, 1);
#undef K1
#undef STAGE1

    int crow = (w >> 2) * 64 + (kq << 2);
    int ccol = (w & 3) * 32 + l15;
#pragma unroll
    for (int mi = 0; mi < 4; ++mi) {
#pragma unroll
        for (int ni = 0; ni < 2; ++ni) {
            int col = ccol + ni * 16;
            float bias = b1[e * HDIM + h0 + n0 + col];
#pragma unroll
            for (int j = 0; j < 4; ++j) {
                int row = crow + mi * 16 + j;
                if (row < rows) {
                    float v = acc[mi][ni][j] + bias;
                    hbuf[(size_t)(m0 + row) * hlen + (n0 + col)] = f2bf(geluf(v));
                }
            }
        }
    }
}

__global__ __launch_bounds__(512) void gemm2_kernel(
    const short* __restrict__ hbuf, const short* __restrict__ w2t,
    const float* __restrict__ b2, const int* __restrict__ offs,
    const int* __restrict__ tile_e, const int* __restrict__ tile_m0,
    const int* __restrict__ list_tok, const float* __restrict__ list_w,
    short* __restrict__ ybuf, float* __restrict__ out,
    int h0, int hlen, int mode, int t0, int tc)
{
    int ty, xn;
    xcd_decode((int)blockIdx.x, DDIM / GBN2, tc, ty, xn);
    int tb = t0 + ty;
    if (tb >= offs[17]) return;
    int e = tile_e[tb], m0 = tile_m0[tb];
    int rows = offs[e + 1] - m0; if (rows > GBM) rows = GBM;
    int n0 = xn * GBN2;                  // output d coordinate
    int tid = threadIdx.x, l = tid & 63, w = tid >> 6;

    __shared__ __align__(16) short As[3][GBM * BK];    // 3 x 8 KiB
    __shared__ __align__(16) short Bs[3][GBN2 * BK];   // 3 x 8 KiB = 48 KB total

    int arow = w * 16 + (l >> 2);
    int aslot = (l & 3) ^ ((arow >> 1) & 3);
    int aslotg = m0 + arow; if (aslotg >= NSLOT) aslotg = NSLOT - 1;
    const short* gA = hbuf + (size_t)aslotg * hlen + aslot * 8;
    int brow = w * 16 + (l >> 2);
    int bslot = (l & 3) ^ ((brow >> 1) & 3);
    const short* gB = w2t + ((size_t)e * DDIM + (size_t)(n0 + brow)) * HDIM + h0 + bslot * 8;

    int l15 = l & 15, kq = l >> 4;
    int aoff[4], boff[2];
#pragma unroll
    for (int mi = 0; mi < 4; ++mi) {
        int R = (w >> 2) * 64 + mi * 16 + l15;
        aoff[mi] = R * BK + ((kq ^ ((R >> 1) & 3)) * 8);
    }
#pragma unroll
    for (int ni = 0; ni < 2; ++ni) {
        int S = (w & 3) * 32 + ni * 16 + l15;
        boff[ni] = S * BK + ((kq ^ ((S >> 1) & 3)) * 8);
    }

    f32x4 vzero = {0.0f, 0.0f, 0.0f, 0.0f};
    f32x4 acc[4][2];
#pragma unroll
    for (int i = 0; i < 4; ++i)
#pragma unroll
        for (int j = 0; j < 2; ++j) acc[i][j] = vzero;

#define STAGE2(T, B) {                                            \
        gload16(gA + (T) * BK, &As[B][w * 512]);                  \
        gload16(gB + (T) * BK, &Bs[B][w * 512]); }

#define K2(T, CB, DOST, LAST) {                                   \
        if (LAST) asm volatile("s_waitcnt vmcnt(0)" ::: "memory");\
        else      asm volatile("s_waitcnt vmcnt(2)" ::: "memory");\
        __builtin_amdgcn_s_barrier();                             \
        __builtin_amdgcn_sched_barrier(0);                        \
        if (DOST) STAGE2((T) + 2, ((CB) + 2) % 3);                \
        short8 af[4], bv[2];                                      \
        _Pragma("unroll")                                         \
        for (int mi = 0; mi < 4; ++mi)                            \
            af[mi] = *(const short8*)(&As[CB][0] + aoff[mi]);     \
        _Pragma("unroll")                                         \
        for (int ni = 0; ni < 2; ++ni)                            \
            bv[ni] = *(const short8*)(&Bs[CB][0] + boff[ni]);     \
        __builtin_amdgcn_s_setprio(1);                            \
        _Pragma("unroll")                                         \
        for (int mi = 0; mi < 4; ++mi)                            \
            _Pragma("unroll")                                     \
            for (int ni = 0; ni < 2; ++ni)                        \
                acc[mi][ni] = __builtin_amdgcn_mfma_f32_16x16x32_bf16( \
                    af[mi], bv[ni], acc[mi][ni], 0, 0, 0);        \
        __builtin_amdgcn_s_setprio(0);                            \
    }

    // nt = 64 K-steps: 20 full groups (t=0..59) + 4-step tail
    STAGE2(0, 0);
    STAGE2(1, 1);
#pragma unroll 1
    for (int g = 0; g < 20; ++g) {
        int t3 = 3 * g;
        K2(t3 + 0, 0, 1, 0);
        K2(t3 + 1, 1, 1, 0);
        K2(t3 + 2, 2, 1, 0);
    }
    K2(60, 0, 1, 0);
    K2(61, 1, 1, 0);
    K2(62, 2, 0, 0);
    K2(63, 0, 0, 1);
#undef K2
#undef STAGE2

    int crow = (w >> 2) * 64 + (kq << 2);
    int ccol = (w & 3) * 32 + l15;
#pragma unroll
    for (int mi = 0; mi < 4; ++mi) {
#pragma unroll
        for (int ni = 0; ni < 2; ++ni) {
            int col = ccol + ni * 16;
            float bias = (h0 == 0) ? b2[e * DDIM + n0 + col] : 0.0f;
#pragma unroll
            for (int j = 0; j < 4; ++j) {
                int row = crow + mi * 16 + j;
                if (row < rows) {
                    float v = acc[mi][ni][j] + bias;
                    if (mode == 0) {  // full-K path: single bf16 write by slot
                        ybuf[(size_t)(m0 + row) * DDIM + n0 + col] = f2bf(v);
                    } else {          // atomic path: token/weight from global (L2)
                        int tokr = list_tok[m0 + row];
                        float wr = list_w[m0 + row];
                        atomicAdd(&out[(size_t)tokr * DDIM + n0 + col], wr * v);
                    }
                }
            }
        }
    }
}

// out[t] = w0*ybuf[pos0] + w1*ybuf[pos1]  (ybuf bf16, 8 cols/thread)
__global__ __launch_bounds__(256) void combine_kernel(
    const short* __restrict__ ybuf, const int* __restrict__ pos_tk,
    const float* __restrict__ tok_w, float* __restrict__ out)
{
    int i = blockIdx.x * 256 + threadIdx.x;   // over T_TOK * 64 units
    int t = i >> 6, c = (i & 63) * 8;
    float w0 = tok_w[2 * t], w1 = tok_w[2 * t + 1];
    int p0 = pos_tk[2 * t], p1 = pos_tk[2 * t + 1];
    short8 a = *(const short8*)(ybuf + (size_t)p0 * DDIM + c);
    short8 b = *(const short8*)(ybuf + (size_t)p1 * DDIM + c);
    float4 o0, o1;
    float* op = (float*)&o0;
#pragma unroll
    for (int j = 0; j < 4; ++j) op[j] = w0 * bf2f(a[j]) + w1 * bf2f(b[j]);
    float* op1 = (float*)&o1;
#pragma unroll
    for (int j = 0; j < 4; ++j) op1[j] = w0 * bf2f(a[4 + j]) + w1 * bf2f(b[4 + j]);
    float4* ob = (float4*)(out + (size_t)t * DDIM + c);
    ob[0] = o0;
    ob[1] = o1;
}

// ---------------- launch ----------------

extern "C" void kernel_launch(void* const* d_in, const int* in_sizes, int n_in,
                              void* d_out, int out_size, void* d_ws, size_t ws_size,
                              hipStream_t stream)
{
    const float* x  = (const float*)d_in[0];
    const float* wg = (const float*)d_in[1];
    const float* bg = (const float*)d_in[2];
    const float* w1 = (const float*)d_in[3];
    const float* b1 = (const float*)d_in[4];
    const float* w2 = (const float*)d_in[5];
    const float* b2 = (const float*)d_in[6];
    float* out = (float*)d_out;

    char* p = (char*)d_ws;
    int* offs     = (int*)(p + 128);            // 32 ints
    int* tile_e   = (int*)(p + 256);            // 512 ints
    int* tile_m0  = (int*)(p + 2304);           // 512 ints
    int* bhist    = (int*)(p + 8192);           // 8 KiB
    int* bbase    = (int*)(p + 16384);          // 8 KiB
    int* tok_e    = (int*)(p + 32768);          // 128 KiB
    float* tok_w  = (float*)(p + 32768 + 131072);
    int* list_tok = (int*)(p + 32768 + 262144);
    float* list_w = (float*)(p + 32768 + 393216);
    int* pos_tk   = (int*)(p + 32768 + 524288);
    short* xbf    = (short*)(p + 32768 + 655360);             // 16 MiB
    short* w1t    = xbf + (size_t)T_TOK * DDIM;               // 32 MiB
    short* w2t    = w1t + (size_t)NEXP * DDIM * HDIM;         // 32 MiB
    char* after   = (char*)(w2t + (size_t)NEXP * DDIM * HDIM);
    size_t fixed  = (size_t)(after - p);

    // mode 0: full-K gemm2 + bf16 ybuf + combine (needs hbuf 134 MB + ybuf 33.5 MB)
    // mode 1 fallback: h-chunked gemm2 with atomic out accumulate.
    int mode, hlen = HDIM;
    if (fixed + (size_t)NSLOT * DDIM * 2 + (size_t)NSLOT * HDIM * 2 <= ws_size) {
        mode = 0;
    } else {
        mode = 1;
        hlen = 0;
        for (int hl = HDIM; hl >= 256; hl >>= 1)
            if (fixed + (size_t)NSLOT * hl * 2 <= ws_size) { hlen = hl; break; }
    }
    short* ybuf = (short*)after;
    short* hbuf = (mode == 0) ? (short*)(after + (size_t)NSLOT * DDIM * 2) : (short*)after;

    if (!hlen) { hipMemsetAsync(d_out, 0, (size_t)out_size * sizeof(float), stream); return; }
    if (mode == 1) hipMemsetAsync(d_out, 0, (size_t)out_size * sizeof(float), stream);

    gate_kernel<<<T_TOK / 4, 256, 0, stream>>>(x, wg, bg, tok_e, tok_w, xbf);
    hist_kernel<<<NHB, 256, 0, stream>>>(tok_e, bhist);
    scan_kernel<<<1, 64, 0, stream>>>(bhist, offs, bbase, tile_e, tile_m0);
    scatter_kernel<<<NHB, 256, 0, stream>>>(tok_e, tok_w, bbase, list_tok, list_w, pos_tk);
    wtrans_kernel<<<dim3(HDIM / 64, DDIM / 64, NEXP), 256, 0, stream>>>(w1, w1t, DDIM, HDIM);
    wtrans_kernel<<<dim3(DDIM / 64, HDIM / 64, NEXP), 256, 0, stream>>>(w2, w2t, HDIM, DDIM);

    // single slice; tile-major XCD decode keeps a tile's chunks adjacent.
    for (int h0 = 0; h0 < HDIM; h0 += hlen) {
        for (int t0 = 0; t0 < MAXTILE; t0 += TSLICE) {
            int tc = MAXTILE - t0; if (tc > TSLICE) tc = TSLICE;
            gemm1_kernel<<<(hlen / GBN1) * tc, 512, 0, stream>>>(
                xbf, w1t, b1, offs, tile_e, tile_m0, list_tok, hbuf, h0, hlen, t0, tc);
            gemm2_kernel<<<(DDIM / GBN2) * tc, 512, 0, stream>>>(
                hbuf, w2t, b2, offs, tile_e, tile_m0, list_tok, list_w,
                ybuf, out, h0, hlen, mode, t0, tc);
        }
    }
    if (mode == 0)
        combine_kernel<<<T_TOK * 64 / 256, 256, 0, stream>>>(ybuf, pos_tk, tok_w, out);
}